// Round 1
// baseline (4004.934 us; speedup 1.0000x reference)
//
#include <hip/hip_runtime.h>

typedef unsigned short u16;
using u16x8  = __attribute__((ext_vector_type(8))) unsigned short;
using bf16x8 = __attribute__((ext_vector_type(8))) __bf16;
using f32x4  = __attribute__((ext_vector_type(4))) float;

#define NKVAL 32768
#define NQVAL 262144
#define EVAL  524288

__device__ __forceinline__ u16 f2bf(float f) {
  unsigned u = __float_as_uint(f);
  u = (u + 0x7fffu + ((u >> 16) & 1u)) >> 16;   // RNE
  return (u16)u;
}
__device__ __forceinline__ float bf2f(u16 h) {
  return __uint_as_float(((unsigned)h) << 16);
}

// ---------------- degree ----------------
__global__ __launch_bounds__(256) void deg_k(const int* __restrict__ dst, float* __restrict__ deg) {
  int e = blockIdx.x * 256 + threadIdx.x;
  if (e < EVAL) atomicAdd(&deg[dst[e]], 1.0f);
}

// ---------------- layer-0 aggregation (F=3, global atomics) ----------------
__global__ __launch_bounds__(256) void agg0_k(const int* __restrict__ src, const int* __restrict__ dst,
                                              const float* __restrict__ known, float* __restrict__ m0) {
  int e = blockIdx.x * 256 + threadIdx.x;
  if (e < EVAL) {
    int s = src[e], d = dst[e];
    atomicAdd(&m0[d * 3 + 0], known[s * 3 + 0]);
    atomicAdd(&m0[d * 3 + 1], known[s * 3 + 1]);
    atomicAdd(&m0[d * 3 + 2], known[s * 3 + 2]);
  }
}

// ---------------- K=3 dense: Y = relu((X[/deg]) @ W[3,512] + b) -> bf16 ----------------
__global__ __launch_bounds__(256) void k3_dense(const float* __restrict__ X, const float* __restrict__ deg,
                                                const float* __restrict__ W, const float* __restrict__ Bb,
                                                u16* __restrict__ Y, int M) {
  int id = blockIdx.x * 256 + threadIdx.x;
  if (id >= M * 512) return;
  int i = id >> 9, j = id & 511;
  float x0 = X[i * 3 + 0], x1 = X[i * 3 + 1], x2 = X[i * 3 + 2];
  if (deg) {
    float inv = 1.0f / fmaxf(deg[i], 1.0f);
    x0 *= inv; x1 *= inv; x2 *= inv;
  }
  float v = fmaf(x0, W[j], Bb[j]);
  v = fmaf(x1, W[512 + j], v);
  v = fmaf(x2, W[1024 + j], v);
  Y[id] = f2bf(fmaxf(v, 0.0f));
}

// ---------------- GCN aggregation: Mo = segsum(H[src])/deg, bf16 in/out ----------------
// block = (graph g, 8-col slice). LDS acc padded [1024][9] to break bank aliasing.
__global__ __launch_bounds__(256) void agg_gcn(const u16* __restrict__ H, const int* __restrict__ src,
                                               const int* __restrict__ dst, const float* __restrict__ deg,
                                               u16* __restrict__ Mo) {
  __shared__ float acc[1024][9];
  const int g = blockIdx.y, c0 = blockIdx.x * 8, t = threadIdx.x;
  for (int i = t; i < 1024 * 9; i += 256) ((float*)acc)[i] = 0.0f;
  __syncthreads();
  const int e0 = g * 16384;  // NK_PER*DEG edges per graph
  for (int e = e0 + t; e < e0 + 16384; e += 256) {
    int s = src[e];
    int d = dst[e] - (g << 10);
    u16x8 hv = *(const u16x8*)(H + (size_t)s * 512 + c0);
#pragma unroll
    for (int j = 0; j < 8; j++) atomicAdd(&acc[d][j], bf2f(hv[j]));
  }
  __syncthreads();
  for (int i = t; i < 1024 * 8; i += 256) {
    int r = i >> 3, j = i & 7;
    float inv = 1.0f / fmaxf(deg[(g << 10) + r], 1.0f);
    Mo[((size_t)(g << 10) + r) * 512 + c0 + j] = f2bf(acc[r][j] * inv);
  }
}

// ---------------- weight cast+transpose: WT[n][k] = bf16(W[k][n]), 512x512 ----------------
__global__ __launch_bounds__(256) void wcast_t(const float* __restrict__ W, u16* __restrict__ WT) {
  __shared__ u16 tile[64][72];
  const int k0 = blockIdx.y * 64, n0 = blockIdx.x * 64, t = threadIdx.x;
#pragma unroll
  for (int i = 0; i < 16; i++) {
    int kk = (t >> 6) * 16 + i, nn = t & 63;
    tile[nn][kk] = f2bf(W[(size_t)(k0 + kk) * 512 + n0 + nn]);
  }
  __syncthreads();
#pragma unroll
  for (int i = 0; i < 16; i++) {
    int nn = (t >> 6) * 16 + i, kk = t & 63;
    WT[(size_t)(n0 + nn) * 512 + k0 + kk] = tile[nn][kk];
  }
}

// ---------------- pooling: pooled[g] = mean rows of H2 graph block ----------------
__global__ __launch_bounds__(256) void pool_k(const u16* __restrict__ H2, float* __restrict__ pooled) {
  const int g = blockIdx.y, chunk = blockIdx.x, t = threadIdx.x;
  float s0 = 0.f, s1 = 0.f;
  const int r0 = chunk * 128;
  for (int r = r0; r < r0 + 128; r++) {
    const u16* row = H2 + ((size_t)(g << 10) + r) * 512;
    s0 += bf2f(row[t]);
    s1 += bf2f(row[t + 256]);
  }
  atomicAdd(&pooled[g * 512 + t], s0 * (1.0f / 1024.0f));
  atomicAdd(&pooled[g * 512 + t + 256], s1 * (1.0f / 1024.0f));
}

// ---------------- field = pooled @ gc_wr + gc_br  (fp32, tiny) ----------------
__global__ __launch_bounds__(256) void field_k(const float* __restrict__ pooled, const float* __restrict__ wr,
                                               const float* __restrict__ br, float* __restrict__ field) {
  int id = blockIdx.x * 256 + threadIdx.x;  // 32*512
  int g = id >> 9, j = id & 511;
  float s = br[j];
  for (int k = 0; k < 512; k++) s = fmaf(pooled[g * 512 + k], wr[k * 512 + j], s);
  field[id] = s;
}

// ---------------- out init: out = bo2 broadcast ----------------
__global__ __launch_bounds__(256) void out_init(float* __restrict__ out, const float* __restrict__ bo2) {
  int id = blockIdx.x * 256 + threadIdx.x;
  if (id < NQVAL * 3) out[id] = bo2[id % 3];
}

// ---------------- GEMM: C = epilogue(A[M,512] @ BT[512,512]^T + bias) ----------------
// MODE 0: C = relu(.) -> bf16       (GCN hidden layers)
// MODE 1: C = (.) * field[row>>13]  (trunk layer 2 fused with segment-broadcast mult)
// MODE 2: out += relu(.) @ wo2      (out layer 1 fused with final [512,3] GEMM, atomics)
template <int MODE>
__global__ __launch_bounds__(256) void gemm_bt(const u16* __restrict__ A, const u16* __restrict__ BT,
                                               const float* __restrict__ bias, const float* __restrict__ field,
                                               const float* __restrict__ wo2, u16* __restrict__ C,
                                               float* __restrict__ outp, int K) {
  __shared__ u16 As[128 * 32];
  __shared__ u16 Bs[128 * 32];
  const int t = threadIdx.x;
  const int wave = t >> 6, lane = t & 63;
  const int wr = wave >> 1, wc = wave & 1;   // 2x2 wave grid, 64x64 out each
  const int lr = lane & 15, kg = lane >> 4;  // frag row/col, k-group
  const long m0 = (long)blockIdx.y * 128;
  const int n0 = blockIdx.x * 128;
  f32x4 acc[4][4] = {};
  const int r = t >> 2, c = (t & 3) * 8;
  const u16* Ab = A + m0 * K + (long)r * K + c;
  const u16* Bb = BT + (long)(n0 + r) * K + c;
  for (int kt = 0; kt < K; kt += 32) {
    u16x8 va0 = *(const u16x8*)(Ab + kt);
    u16x8 va1 = *(const u16x8*)(Ab + 64 * K + kt);
    u16x8 vb0 = *(const u16x8*)(Bb + kt);
    u16x8 vb1 = *(const u16x8*)(Bb + 64 * K + kt);
    __syncthreads();
    *(u16x8*)&As[r * 32 + c] = va0;
    *(u16x8*)&As[(64 + r) * 32 + c] = va1;
    *(u16x8*)&Bs[r * 32 + c] = vb0;
    *(u16x8*)&Bs[(64 + r) * 32 + c] = vb1;
    __syncthreads();
    bf16x8 af[4], bfv[4];
#pragma unroll
    for (int i = 0; i < 4; i++) {
      af[i]  = *(const bf16x8*)&As[(wr * 64 + i * 16 + lr) * 32 + kg * 8];
      bfv[i] = *(const bf16x8*)&Bs[(wc * 64 + i * 16 + lr) * 32 + kg * 8];
    }
#pragma unroll
    for (int mi = 0; mi < 4; mi++)
#pragma unroll
      for (int ni = 0; ni < 4; ni++)
        acc[mi][ni] = __builtin_amdgcn_mfma_f32_16x16x32_bf16(af[mi], bfv[ni], acc[mi][ni], 0, 0, 0);
  }

  if (MODE == 2) {
    // z2 = relu(acc + bo1); out += z2 @ wo2  (reduce over this block's 128 cols)
    float po[4][4][3];
#pragma unroll
    for (int mi = 0; mi < 4; mi++)
#pragma unroll
      for (int r2 = 0; r2 < 4; r2++)
#pragma unroll
        for (int o = 0; o < 3; o++) po[mi][r2][o] = 0.0f;
#pragma unroll
    for (int ni = 0; ni < 4; ni++) {
      int col = n0 + wc * 64 + ni * 16 + lr;
      float bb = bias[col];
      float wa = wo2[col * 3 + 0], wb = wo2[col * 3 + 1], wcv = wo2[col * 3 + 2];
#pragma unroll
      for (int mi = 0; mi < 4; mi++)
#pragma unroll
        for (int r2 = 0; r2 < 4; r2++) {
          float v = fmaxf(acc[mi][ni][r2] + bb, 0.0f);
          po[mi][r2][0] = fmaf(v, wa, po[mi][r2][0]);
          po[mi][r2][1] = fmaf(v, wb, po[mi][r2][1]);
          po[mi][r2][2] = fmaf(v, wcv, po[mi][r2][2]);
        }
    }
#pragma unroll
    for (int s = 1; s < 16; s <<= 1)
#pragma unroll
      for (int mi = 0; mi < 4; mi++)
#pragma unroll
        for (int r2 = 0; r2 < 4; r2++)
#pragma unroll
          for (int o = 0; o < 3; o++) po[mi][r2][o] += __shfl_xor(po[mi][r2][o], s, 64);
    if (lr == 0) {
#pragma unroll
      for (int mi = 0; mi < 4; mi++)
#pragma unroll
        for (int r2 = 0; r2 < 4; r2++) {
          long row = m0 + wr * 64 + mi * 16 + kg * 4 + r2;
#pragma unroll
          for (int o = 0; o < 3; o++) atomicAdd(&outp[row * 3 + o], po[mi][r2][o]);
        }
    }
  } else {
    const int gq = (int)(m0 >> 13);  // 8192 query rows per graph
#pragma unroll
    for (int mi = 0; mi < 4; mi++)
#pragma unroll
      for (int ni = 0; ni < 4; ni++) {
        int col = n0 + wc * 64 + ni * 16 + lr;
        float bb = bias[col];
        float fm = (MODE == 1) ? field[gq * 512 + col] : 0.0f;
#pragma unroll
        for (int r2 = 0; r2 < 4; r2++) {
          long row = m0 + wr * 64 + mi * 16 + kg * 4 + r2;
          float v = acc[mi][ni][r2] + bb;
          v = (MODE == 1) ? v * fm : fmaxf(v, 0.0f);
          C[row * 512 + col] = f2bf(v);
        }
      }
  }
}

extern "C" void kernel_launch(void* const* d_in, const int* in_sizes, int n_in,
                              void* d_out, int out_size, void* d_ws, size_t ws_size,
                              hipStream_t stream) {
  const float* known = (const float*)d_in[0];
  const float* nodes = (const float*)d_in[1];
  const int* esrc = (const int*)d_in[2];
  const int* edst = (const int*)d_in[3];
  const float* gc_w0 = (const float*)d_in[6];
  const float* gc_b0 = (const float*)d_in[7];
  const float* gc_w1 = (const float*)d_in[8];
  const float* gc_b1 = (const float*)d_in[9];
  const float* gc_w2 = (const float*)d_in[10];
  const float* gc_b2 = (const float*)d_in[11];
  const float* gc_wr = (const float*)d_in[12];
  const float* gc_br = (const float*)d_in[13];
  const float* wt1 = (const float*)d_in[14];
  const float* bt1 = (const float*)d_in[15];
  const float* wt2 = (const float*)d_in[16];
  const float* bt2 = (const float*)d_in[17];
  const float* wo1 = (const float*)d_in[18];
  const float* bo1 = (const float*)d_in[19];
  const float* wo2 = (const float*)d_in[20];
  const float* bo2 = (const float*)d_in[21];
  float* out = (float*)d_out;
  (void)in_sizes; (void)n_in; (void)out_size; (void)ws_size;

  char* ws = (char*)d_ws;
  size_t off = 0;
  auto alloc = [&](size_t n) -> void* {
    void* p = ws + off;
    off += (n + 255) & ~(size_t)255;
    return p;
  };
  u16* w1T  = (u16*)alloc(512 * 512 * 2);
  u16* w2T  = (u16*)alloc(512 * 512 * 2);
  u16* wt2T = (u16*)alloc(512 * 512 * 2);
  u16* wo1T = (u16*)alloc(512 * 512 * 2);
  float* deg    = (float*)alloc(NKVAL * 4);
  float* m0     = (float*)alloc(NKVAL * 3 * 4);
  float* pooled = (float*)alloc(32 * 512 * 4);
  float* field  = (float*)alloc(32 * 512 * 4);
  u16* bufA = (u16*)alloc((size_t)NKVAL * 512 * 2);
  u16* bufB = (u16*)alloc((size_t)NKVAL * 512 * 2);
  u16* bufC = (u16*)alloc((size_t)NKVAL * 512 * 2);
  u16* t1c  = (u16*)alloc((size_t)32768 * 512 * 2);
  u16* zc   = (u16*)alloc((size_t)32768 * 512 * 2);
  // total ws use ~165 MiB

  hipMemsetAsync(deg, 0, NKVAL * 4, stream);
  hipMemsetAsync(m0, 0, NKVAL * 3 * 4, stream);
  hipMemsetAsync(pooled, 0, 32 * 512 * 4, stream);

  wcast_t<<<dim3(8, 8), 256, 0, stream>>>(gc_w1, w1T);
  wcast_t<<<dim3(8, 8), 256, 0, stream>>>(gc_w2, w2T);
  wcast_t<<<dim3(8, 8), 256, 0, stream>>>(wt2, wt2T);
  wcast_t<<<dim3(8, 8), 256, 0, stream>>>(wo1, wo1T);

  deg_k<<<EVAL / 256, 256, 0, stream>>>(edst, deg);
  agg0_k<<<EVAL / 256, 256, 0, stream>>>(esrc, edst, known, m0);
  // h0 = relu((m0/deg) @ gc_w0 + b0)
  k3_dense<<<NKVAL * 512 / 256, 256, 0, stream>>>(m0, deg, gc_w0, gc_b0, bufA, NKVAL);
  // m1 = segsum(h0[src])/deg
  agg_gcn<<<dim3(64, 32), 256, 0, stream>>>(bufA, esrc, edst, deg, bufB);
  // h1 = relu(m1 @ W1 + b1)
  gemm_bt<0><<<dim3(4, NKVAL / 128), 256, 0, stream>>>(bufB, w1T, gc_b1, nullptr, nullptr, bufC, nullptr, 512);
  // m2
  agg_gcn<<<dim3(64, 32), 256, 0, stream>>>(bufC, esrc, edst, deg, bufA);
  // h2
  gemm_bt<0><<<dim3(4, NKVAL / 128), 256, 0, stream>>>(bufA, w2T, gc_b2, nullptr, nullptr, bufB, nullptr, 512);
  pool_k<<<dim3(8, 32), 256, 0, stream>>>(bufB, pooled);
  field_k<<<64, 256, 0, stream>>>(pooled, gc_wr, gc_br, field);

  out_init<<<NQVAL * 3 / 256, 256, 0, stream>>>(out, bo2);
  for (int ch = 0; ch < 8; ch++) {
    long rowoff = (long)ch * 32768;
    // t1 = relu(nodes @ wt1 + bt1)
    k3_dense<<<32768 * 512 / 256, 256, 0, stream>>>(nodes + rowoff * 3, nullptr, wt1, bt1, t1c, 32768);
    // z = (t1 @ wt2 + bt2) * field[seg]
    gemm_bt<1><<<dim3(4, 256), 256, 0, stream>>>(t1c, wt2T, bt2, field + (rowoff >> 13) * 512, nullptr, zc, nullptr, 512);
    // out += relu(z @ wo1 + bo1) @ wo2   (bo2 pre-initialized)
    gemm_bt<2><<<dim3(4, 256), 256, 0, stream>>>(zc, wo1T, bo1, nullptr, wo2, nullptr, out + rowoff * 3, 512);
  }
}

// Round 2
// 1370.398 us; speedup vs baseline: 2.9225x; 2.9225x over previous
//
#include <hip/hip_runtime.h>

typedef unsigned short u16;
using u16x8  = __attribute__((ext_vector_type(8))) unsigned short;
using bf16x8 = __attribute__((ext_vector_type(8))) __bf16;
using f32x4  = __attribute__((ext_vector_type(4))) float;

#define NKVAL 32768
#define NQVAL 262144
#define EVAL  524288

__device__ __forceinline__ u16 f2bf(float f) {
  unsigned u = __float_as_uint(f);
  u = (u + 0x7fffu + ((u >> 16) & 1u)) >> 16;   // RNE
  return (u16)u;
}
__device__ __forceinline__ float bf2f(u16 h) {
  return __uint_as_float(((unsigned)h) << 16);
}
__device__ __forceinline__ void gl2lds16(const u16* g, u16* l) {
  __builtin_amdgcn_global_load_lds((const __attribute__((address_space(1))) void*)g,
                                   (__attribute__((address_space(3))) void*)l, 16, 0, 0);
}

// ---------------- int degree ----------------
__global__ __launch_bounds__(256) void degcnt_k(const int* __restrict__ dst, int* __restrict__ cnt) {
  int e = blockIdx.x * 256 + threadIdx.x;
  if (e < EVAL) atomicAdd(&cnt[dst[e]], 1);
}

// ---------------- exclusive scan over cnt[NKVAL] -> off[NKVAL+1], single block ----------------
__global__ __launch_bounds__(1024) void scan_k(const int* __restrict__ cnt, int* __restrict__ off) {
  __shared__ int part[1024];
  const int t = threadIdx.x;
  const int base = t * 32;
  int local[32];
  int s = 0;
#pragma unroll
  for (int i = 0; i < 32; i++) { local[i] = s; s += cnt[base + i]; }
  part[t] = s;
  __syncthreads();
  for (int d = 1; d < 1024; d <<= 1) {
    int v = (t >= d) ? part[t - d] : 0;
    __syncthreads();
    part[t] += v;
    __syncthreads();
  }
  int pre = (t == 0) ? 0 : part[t - 1];
#pragma unroll
  for (int i = 0; i < 32; i++) off[base + i] = pre + local[i];
  if (t == 1023) off[NKVAL] = pre + s;
}

// ---------------- scatter edges into CSR-by-dst ----------------
__global__ __launch_bounds__(256) void scatter_k(const int* __restrict__ src, const int* __restrict__ dst,
                                                 const int* __restrict__ off, int* __restrict__ cur,
                                                 int* __restrict__ srcs_sorted) {
  int e = blockIdx.x * 256 + threadIdx.x;
  if (e < EVAL) {
    int d = dst[e];
    int p = atomicAdd(&cur[d], 1);
    srcs_sorted[off[d] + p] = src[e];
  }
}

// ---------------- layer-0 aggregation (F=3, global atomics) ----------------
__global__ __launch_bounds__(256) void agg0_k(const int* __restrict__ src, const int* __restrict__ dst,
                                              const float* __restrict__ known, float* __restrict__ m0) {
  int e = blockIdx.x * 256 + threadIdx.x;
  if (e < EVAL) {
    int s = src[e], d = dst[e];
    atomicAdd(&m0[d * 3 + 0], known[s * 3 + 0]);
    atomicAdd(&m0[d * 3 + 1], known[s * 3 + 1]);
    atomicAdd(&m0[d * 3 + 2], known[s * 3 + 2]);
  }
}

// ---------------- K=3 dense: Y = relu((X[/cnt]) @ W[3,512] + b) -> bf16 ----------------
__global__ __launch_bounds__(256) void k3_dense(const float* __restrict__ X, const int* __restrict__ cnt,
                                                const float* __restrict__ W, const float* __restrict__ Bb,
                                                u16* __restrict__ Y, int M) {
  int id = blockIdx.x * 256 + threadIdx.x;
  if (id >= M * 512) return;
  int i = id >> 9, j = id & 511;
  float x0 = X[i * 3 + 0], x1 = X[i * 3 + 1], x2 = X[i * 3 + 2];
  if (cnt) {
    float inv = 1.0f / fmaxf((float)cnt[i], 1.0f);
    x0 *= inv; x1 *= inv; x2 *= inv;
  }
  float v = fmaf(x0, W[j], Bb[j]);
  v = fmaf(x1, W[512 + j], v);
  v = fmaf(x2, W[1024 + j], v);
  Y[id] = f2bf(fmaxf(v, 0.0f));
}

// ---------------- GCN aggregation via CSR: wave per dst node, regs only ----------------
__global__ __launch_bounds__(256) void agg_csr(const u16* __restrict__ H, const int* __restrict__ off,
                                               const int* __restrict__ srcs, u16* __restrict__ Mo) {
  const int node = blockIdx.x * 4 + (threadIdx.x >> 6);
  const int lane = threadIdx.x & 63;
  const int beg = off[node], end = off[node + 1];
  const int c0 = lane * 8;
  float acc[8] = {0, 0, 0, 0, 0, 0, 0, 0};
  int e = beg;
  for (; e + 4 <= end; e += 4) {
    int s0 = srcs[e], s1 = srcs[e + 1], s2 = srcs[e + 2], s3 = srcs[e + 3];
    u16x8 h0 = *(const u16x8*)(H + (size_t)s0 * 512 + c0);
    u16x8 h1 = *(const u16x8*)(H + (size_t)s1 * 512 + c0);
    u16x8 h2 = *(const u16x8*)(H + (size_t)s2 * 512 + c0);
    u16x8 h3 = *(const u16x8*)(H + (size_t)s3 * 512 + c0);
#pragma unroll
    for (int j = 0; j < 8; j++)
      acc[j] += (bf2f(h0[j]) + bf2f(h1[j])) + (bf2f(h2[j]) + bf2f(h3[j]));
  }
  for (; e < end; e++) {
    int s = srcs[e];
    u16x8 hv = *(const u16x8*)(H + (size_t)s * 512 + c0);
#pragma unroll
    for (int j = 0; j < 8; j++) acc[j] += bf2f(hv[j]);
  }
  float inv = 1.0f / fmaxf((float)(end - beg), 1.0f);
  u16x8 o;
#pragma unroll
  for (int j = 0; j < 8; j++) o[j] = f2bf(acc[j] * inv);
  *(u16x8*)(Mo + (size_t)node * 512 + c0) = o;
}

// ---------------- weight cast+transpose: WT[n][k] = bf16(W[k][n]), 512x512 ----------------
__global__ __launch_bounds__(256) void wcast_t(const float* __restrict__ W, u16* __restrict__ WT) {
  __shared__ u16 tile[64][72];
  const int k0 = blockIdx.y * 64, n0 = blockIdx.x * 64, t = threadIdx.x;
#pragma unroll
  for (int i = 0; i < 16; i++) {
    int kk = (t >> 6) * 16 + i, nn = t & 63;
    tile[nn][kk] = f2bf(W[(size_t)(k0 + kk) * 512 + n0 + nn]);
  }
  __syncthreads();
#pragma unroll
  for (int i = 0; i < 16; i++) {
    int nn = (t >> 6) * 16 + i, kk = t & 63;
    WT[(size_t)(n0 + nn) * 512 + k0 + kk] = tile[nn][kk];
  }
}

// ---------------- pooling: pooled[g] = mean rows of H2 graph block ----------------
__global__ __launch_bounds__(256) void pool_k(const u16* __restrict__ H2, float* __restrict__ pooled) {
  const int g = blockIdx.y, chunk = blockIdx.x, t = threadIdx.x;
  float s0 = 0.f, s1 = 0.f;
  const int r0 = chunk * 128;
  for (int r = r0; r < r0 + 128; r++) {
    const u16* row = H2 + ((size_t)(g << 10) + r) * 512;
    s0 += bf2f(row[t]);
    s1 += bf2f(row[t + 256]);
  }
  atomicAdd(&pooled[g * 512 + t], s0 * (1.0f / 1024.0f));
  atomicAdd(&pooled[g * 512 + t + 256], s1 * (1.0f / 1024.0f));
}

// ---------------- field = pooled @ gc_wr + gc_br  (fp32, tiny) ----------------
__global__ __launch_bounds__(256) void field_k(const float* __restrict__ pooled, const float* __restrict__ wr,
                                               const float* __restrict__ br, float* __restrict__ field) {
  int id = blockIdx.x * 256 + threadIdx.x;  // 32*512
  int g = id >> 9, j = id & 511;
  float s = br[j];
  for (int k = 0; k < 512; k++) s = fmaf(pooled[g * 512 + k], wr[k * 512 + j], s);
  field[id] = s;
}

// ---------------- out init: out = bo2 broadcast ----------------
__global__ __launch_bounds__(256) void out_init(float* __restrict__ out, const float* __restrict__ bo2) {
  int id = blockIdx.x * 256 + threadIdx.x;
  if (id < NQVAL * 3) out[id] = bo2[id % 3];
}

// ---------------- GEMM: C = epilogue(A[M,512] @ BT[512,512]^T + bias) ----------------
// 128x128 tile, BK=32, global_load_lds(16B) staging (m97 structure).
// MODE 0: C = relu(.) -> bf16       (GCN hidden layers)
// MODE 1: C = (.) * field[row>>13]  (trunk layer 2 fused with segment-broadcast mult)
// MODE 2: out += relu(.) @ wo2      (out layer 1 fused with final [512,3] GEMM, atomics)
template <int MODE>
__global__ __launch_bounds__(256) void gemm_bt(const u16* __restrict__ A, const u16* __restrict__ BT,
                                               const float* __restrict__ bias, const float* __restrict__ field,
                                               const float* __restrict__ wo2, u16* __restrict__ C,
                                               float* __restrict__ outp) {
  constexpr int K = 512;
  __shared__ u16 As[128 * 32];
  __shared__ u16 Bs[128 * 32];
  const int t = threadIdx.x;
  const int wave = t >> 6, lane = t & 63;
  const int wr = wave >> 1, wc = wave & 1;   // 2x2 wave grid, 64x64 out each
  const int lr = lane & 15, kg = lane >> 4;  // frag row, k-group
  const long m0 = (long)blockIdx.y * 128;
  const int n0 = blockIdx.x * 128;
  f32x4 acc[4][4] = {};
  // staging addresses: linear LDS (byte t*16), per-lane global source
  const int ar = t >> 2, ac = (t & 3) * 8;
  const u16* gA0 = A + (m0 + ar) * K + ac;
  const u16* gA1 = gA0 + 64 * K;
  const u16* gB0 = BT + (long)(n0 + ar) * K + ac;
  const u16* gB1 = gB0 + 64 * K;
  u16* lA0 = As + t * 8;
  u16* lA1 = As + 2048 + t * 8;
  u16* lB0 = Bs + t * 8;
  u16* lB1 = Bs + 2048 + t * 8;
  for (int kt = 0; kt < K; kt += 32) {
    __syncthreads();
    gl2lds16(gA0 + kt, lA0);
    gl2lds16(gA1 + kt, lA1);
    gl2lds16(gB0 + kt, lB0);
    gl2lds16(gB1 + kt, lB1);
    __syncthreads();
    bf16x8 af[4], bfv[4];
#pragma unroll
    for (int i = 0; i < 4; i++) {
      af[i]  = *(const bf16x8*)&As[(wr * 64 + i * 16 + lr) * 32 + kg * 8];
      bfv[i] = *(const bf16x8*)&Bs[(wc * 64 + i * 16 + lr) * 32 + kg * 8];
    }
#pragma unroll
    for (int mi = 0; mi < 4; mi++)
#pragma unroll
      for (int ni = 0; ni < 4; ni++)
        acc[mi][ni] = __builtin_amdgcn_mfma_f32_16x16x32_bf16(af[mi], bfv[ni], acc[mi][ni], 0, 0, 0);
  }

  if (MODE == 2) {
    // z2 = relu(acc + bo1); out += z2 @ wo2  (reduce over this block's 128 cols)
    float po[4][4][3];
#pragma unroll
    for (int mi = 0; mi < 4; mi++)
#pragma unroll
      for (int r2 = 0; r2 < 4; r2++)
#pragma unroll
        for (int o = 0; o < 3; o++) po[mi][r2][o] = 0.0f;
#pragma unroll
    for (int ni = 0; ni < 4; ni++) {
      int col = n0 + wc * 64 + ni * 16 + lr;
      float bb = bias[col];
      float wa = wo2[col * 3 + 0], wb = wo2[col * 3 + 1], wcv = wo2[col * 3 + 2];
#pragma unroll
      for (int mi = 0; mi < 4; mi++)
#pragma unroll
        for (int r2 = 0; r2 < 4; r2++) {
          float v = fmaxf(acc[mi][ni][r2] + bb, 0.0f);
          po[mi][r2][0] = fmaf(v, wa, po[mi][r2][0]);
          po[mi][r2][1] = fmaf(v, wb, po[mi][r2][1]);
          po[mi][r2][2] = fmaf(v, wcv, po[mi][r2][2]);
        }
    }
#pragma unroll
    for (int s = 1; s < 16; s <<= 1)
#pragma unroll
      for (int mi = 0; mi < 4; mi++)
#pragma unroll
        for (int r2 = 0; r2 < 4; r2++)
#pragma unroll
          for (int o = 0; o < 3; o++) po[mi][r2][o] += __shfl_xor(po[mi][r2][o], s, 64);
    if (lr == 0) {
#pragma unroll
      for (int mi = 0; mi < 4; mi++)
#pragma unroll
        for (int r2 = 0; r2 < 4; r2++) {
          long row = m0 + wr * 64 + mi * 16 + kg * 4 + r2;
#pragma unroll
          for (int o = 0; o < 3; o++) atomicAdd(&outp[row * 3 + o], po[mi][r2][o]);
        }
    }
  } else {
    const int gq = (int)(m0 >> 13);  // 8192 query rows per graph
#pragma unroll
    for (int mi = 0; mi < 4; mi++)
#pragma unroll
      for (int ni = 0; ni < 4; ni++) {
        int col = n0 + wc * 64 + ni * 16 + lr;
        float bb = bias[col];
        float fm = (MODE == 1) ? field[gq * 512 + col] : 0.0f;
#pragma unroll
        for (int r2 = 0; r2 < 4; r2++) {
          long row = m0 + wr * 64 + mi * 16 + kg * 4 + r2;
          float v = acc[mi][ni][r2] + bb;
          v = (MODE == 1) ? v * fm : fmaxf(v, 0.0f);
          C[row * 512 + col] = f2bf(v);
        }
      }
  }
}

extern "C" void kernel_launch(void* const* d_in, const int* in_sizes, int n_in,
                              void* d_out, int out_size, void* d_ws, size_t ws_size,
                              hipStream_t stream) {
  const float* known = (const float*)d_in[0];
  const float* nodes = (const float*)d_in[1];
  const int* esrc = (const int*)d_in[2];
  const int* edst = (const int*)d_in[3];
  const float* gc_w0 = (const float*)d_in[6];
  const float* gc_b0 = (const float*)d_in[7];
  const float* gc_w1 = (const float*)d_in[8];
  const float* gc_b1 = (const float*)d_in[9];
  const float* gc_w2 = (const float*)d_in[10];
  const float* gc_b2 = (const float*)d_in[11];
  const float* gc_wr = (const float*)d_in[12];
  const float* gc_br = (const float*)d_in[13];
  const float* wt1 = (const float*)d_in[14];
  const float* bt1 = (const float*)d_in[15];
  const float* wt2 = (const float*)d_in[16];
  const float* bt2 = (const float*)d_in[17];
  const float* wo1 = (const float*)d_in[18];
  const float* bo1 = (const float*)d_in[19];
  const float* wo2 = (const float*)d_in[20];
  const float* bo2 = (const float*)d_in[21];
  float* out = (float*)d_out;
  (void)in_sizes; (void)n_in; (void)out_size; (void)ws_size;

  char* ws = (char*)d_ws;
  size_t off_b = 0;
  auto alloc = [&](size_t n) -> void* {
    void* p = ws + off_b;
    off_b += (n + 255) & ~(size_t)255;
    return p;
  };
  u16* w1T  = (u16*)alloc(512 * 512 * 2);
  u16* w2T  = (u16*)alloc(512 * 512 * 2);
  u16* wt2T = (u16*)alloc(512 * 512 * 2);
  u16* wo1T = (u16*)alloc(512 * 512 * 2);
  int* cnt   = (int*)alloc(NKVAL * 4);
  int* off   = (int*)alloc((NKVAL + 1) * 4);
  int* cur   = (int*)alloc(NKVAL * 4);
  int* srcs  = (int*)alloc((size_t)EVAL * 4);
  float* m0     = (float*)alloc(NKVAL * 3 * 4);
  float* pooled = (float*)alloc(32 * 512 * 4);
  float* field  = (float*)alloc(32 * 512 * 4);
  u16* bufA = (u16*)alloc((size_t)NKVAL * 512 * 2);
  u16* bufB = (u16*)alloc((size_t)NKVAL * 512 * 2);
  u16* bufC = (u16*)alloc((size_t)NKVAL * 512 * 2);
  u16* t1c  = (u16*)alloc((size_t)32768 * 512 * 2);
  u16* zc   = (u16*)alloc((size_t)32768 * 512 * 2);

  hipMemsetAsync(cnt, 0, NKVAL * 4, stream);
  hipMemsetAsync(cur, 0, NKVAL * 4, stream);
  hipMemsetAsync(m0, 0, NKVAL * 3 * 4, stream);
  hipMemsetAsync(pooled, 0, 32 * 512 * 4, stream);

  wcast_t<<<dim3(8, 8), 256, 0, stream>>>(gc_w1, w1T);
  wcast_t<<<dim3(8, 8), 256, 0, stream>>>(gc_w2, w2T);
  wcast_t<<<dim3(8, 8), 256, 0, stream>>>(wt2, wt2T);
  wcast_t<<<dim3(8, 8), 256, 0, stream>>>(wo1, wo1T);

  degcnt_k<<<EVAL / 256, 256, 0, stream>>>(edst, cnt);
  scan_k<<<1, 1024, 0, stream>>>(cnt, off);
  scatter_k<<<EVAL / 256, 256, 0, stream>>>(esrc, edst, off, cur, srcs);

  agg0_k<<<EVAL / 256, 256, 0, stream>>>(esrc, edst, known, m0);
  // h0 = relu((m0/deg) @ gc_w0 + b0)
  k3_dense<<<NKVAL * 512 / 256, 256, 0, stream>>>(m0, cnt, gc_w0, gc_b0, bufA, NKVAL);
  // m1 = segsum(h0[src])/deg  (CSR gather)
  agg_csr<<<NKVAL / 4, 256, 0, stream>>>(bufA, off, srcs, bufB);
  // h1 = relu(m1 @ W1 + b1)
  gemm_bt<0><<<dim3(4, NKVAL / 128), 256, 0, stream>>>(bufB, w1T, gc_b1, nullptr, nullptr, bufC, nullptr);
  // m2
  agg_csr<<<NKVAL / 4, 256, 0, stream>>>(bufC, off, srcs, bufA);
  // h2
  gemm_bt<0><<<dim3(4, NKVAL / 128), 256, 0, stream>>>(bufA, w2T, gc_b2, nullptr, nullptr, bufB, nullptr);
  pool_k<<<dim3(8, 32), 256, 0, stream>>>(bufB, pooled);
  field_k<<<64, 256, 0, stream>>>(pooled, gc_wr, gc_br, field);

  out_init<<<NQVAL * 3 / 256, 256, 0, stream>>>(out, bo2);
  for (int ch = 0; ch < 8; ch++) {
    long rowoff = (long)ch * 32768;
    // t1 = relu(nodes @ wt1 + bt1)
    k3_dense<<<32768 * 512 / 256, 256, 0, stream>>>(nodes + rowoff * 3, nullptr, wt1, bt1, t1c, 32768);
    // z = (t1 @ wt2 + bt2) * field[seg]
    gemm_bt<1><<<dim3(4, 256), 256, 0, stream>>>(t1c, wt2T, bt2, field + (rowoff >> 13) * 512, nullptr, zc, nullptr);
    // out += relu(z @ wo1 + bo1) @ wo2   (bo2 pre-initialized)
    gemm_bt<2><<<dim3(4, 256), 256, 0, stream>>>(zc, wo1T, bo1, nullptr, wo2, nullptr, out + rowoff * 3);
  }
}

// Round 3
// 974.960 us; speedup vs baseline: 4.1078x; 1.4056x over previous
//
#include <hip/hip_runtime.h>

typedef unsigned short u16;
using u16x8  = __attribute__((ext_vector_type(8))) unsigned short;
using bf16x8 = __attribute__((ext_vector_type(8))) __bf16;
using f32x4  = __attribute__((ext_vector_type(4))) float;

#define NKVAL 32768
#define NQVAL 262144
#define EVAL  524288

__device__ __forceinline__ u16 f2bf(float f) {
  unsigned u = __float_as_uint(f);
  u = (u + 0x7fffu + ((u >> 16) & 1u)) >> 16;   // RNE
  return (u16)u;
}
__device__ __forceinline__ float bf2f(u16 h) {
  return __uint_as_float(((unsigned)h) << 16);
}
__device__ __forceinline__ void gl2lds16(const u16* g, u16* l) {
  __builtin_amdgcn_global_load_lds((const __attribute__((address_space(1))) void*)g,
                                   (__attribute__((address_space(3))) void*)l, 16, 0, 0);
}

// ---------------- int degree ----------------
__global__ __launch_bounds__(256) void degcnt_k(const int* __restrict__ dst, int* __restrict__ cnt) {
  int e = blockIdx.x * 256 + threadIdx.x;
  if (e < EVAL) atomicAdd(&cnt[dst[e]], 1);
}

// ---------------- exclusive scan over cnt[NKVAL] -> off[NKVAL+1], single block ----------------
__global__ __launch_bounds__(1024) void scan_k(const int* __restrict__ cnt, int* __restrict__ off) {
  __shared__ int part[1024];
  const int t = threadIdx.x;
  const int base = t * 32;
  int local[32];
  int s = 0;
#pragma unroll
  for (int i = 0; i < 32; i++) { local[i] = s; s += cnt[base + i]; }
  part[t] = s;
  __syncthreads();
  for (int d = 1; d < 1024; d <<= 1) {
    int v = (t >= d) ? part[t - d] : 0;
    __syncthreads();
    part[t] += v;
    __syncthreads();
  }
  int pre = (t == 0) ? 0 : part[t - 1];
#pragma unroll
  for (int i = 0; i < 32; i++) off[base + i] = pre + local[i];
  if (t == 1023) off[NKVAL] = pre + s;
}

// ---------------- scatter edges into CSR-by-dst ----------------
__global__ __launch_bounds__(256) void scatter_k(const int* __restrict__ src, const int* __restrict__ dst,
                                                 const int* __restrict__ off, int* __restrict__ cur,
                                                 int* __restrict__ srcs_sorted) {
  int e = blockIdx.x * 256 + threadIdx.x;
  if (e < EVAL) {
    int d = dst[e];
    int p = atomicAdd(&cur[d], 1);
    srcs_sorted[off[d] + p] = src[e];
  }
}

// ---------------- layer-0 aggregation via CSR (no atomics) ----------------
__global__ __launch_bounds__(256) void agg0_csr(const int* __restrict__ off, const int* __restrict__ srcs,
                                                const float* __restrict__ known, float* __restrict__ m0) {
  int d = blockIdx.x * 256 + threadIdx.x;
  if (d >= NKVAL) return;
  int b = off[d], e = off[d + 1];
  float a0 = 0.f, a1 = 0.f, a2 = 0.f;
  for (int i = b; i < e; i++) {
    int s = srcs[i];
    a0 += known[s * 3 + 0];
    a1 += known[s * 3 + 1];
    a2 += known[s * 3 + 2];
  }
  m0[d * 3 + 0] = a0;
  m0[d * 3 + 1] = a1;
  m0[d * 3 + 2] = a2;
}

// ---------------- K=3 dense: Y = relu((X[/cnt]) @ W[3,512] + b) -> bf16, vectorized ----------------
__global__ __launch_bounds__(256) void k3_dense(const float* __restrict__ X, const int* __restrict__ cnt,
                                                const float* __restrict__ W, const float* __restrict__ Bb,
                                                u16* __restrict__ Y, int M) {
  int id = blockIdx.x * 256 + threadIdx.x;  // M*64 threads, 8 outputs each
  if (id >= M * 64) return;
  int i = id >> 6, j0 = (id & 63) * 8;
  float x0 = X[i * 3 + 0], x1 = X[i * 3 + 1], x2 = X[i * 3 + 2];
  if (cnt) {
    float inv = 1.0f / fmaxf((float)cnt[i], 1.0f);
    x0 *= inv; x1 *= inv; x2 *= inv;
  }
  u16x8 o;
#pragma unroll
  for (int j = 0; j < 8; j++) {
    float v = fmaf(x0, W[j0 + j], Bb[j0 + j]);
    v = fmaf(x1, W[512 + j0 + j], v);
    v = fmaf(x2, W[1024 + j0 + j], v);
    o[j] = f2bf(fmaxf(v, 0.0f));
  }
  *(u16x8*)(Y + (size_t)i * 512 + j0) = o;
}

// ---------------- GCN aggregation via CSR: wave per dst node, regs only ----------------
__global__ __launch_bounds__(256) void agg_csr(const u16* __restrict__ H, const int* __restrict__ off,
                                               const int* __restrict__ srcs, u16* __restrict__ Mo) {
  const int node = blockIdx.x * 4 + (threadIdx.x >> 6);
  const int lane = threadIdx.x & 63;
  const int beg = off[node], end = off[node + 1];
  const int c0 = lane * 8;
  float acc[8] = {0, 0, 0, 0, 0, 0, 0, 0};
  int e = beg;
  for (; e + 4 <= end; e += 4) {
    int s0 = srcs[e], s1 = srcs[e + 1], s2 = srcs[e + 2], s3 = srcs[e + 3];
    u16x8 h0 = *(const u16x8*)(H + (size_t)s0 * 512 + c0);
    u16x8 h1 = *(const u16x8*)(H + (size_t)s1 * 512 + c0);
    u16x8 h2 = *(const u16x8*)(H + (size_t)s2 * 512 + c0);
    u16x8 h3 = *(const u16x8*)(H + (size_t)s3 * 512 + c0);
#pragma unroll
    for (int j = 0; j < 8; j++)
      acc[j] += (bf2f(h0[j]) + bf2f(h1[j])) + (bf2f(h2[j]) + bf2f(h3[j]));
  }
  for (; e < end; e++) {
    int s = srcs[e];
    u16x8 hv = *(const u16x8*)(H + (size_t)s * 512 + c0);
#pragma unroll
    for (int j = 0; j < 8; j++) acc[j] += bf2f(hv[j]);
  }
  float inv = 1.0f / fmaxf((float)(end - beg), 1.0f);
  u16x8 o;
#pragma unroll
  for (int j = 0; j < 8; j++) o[j] = f2bf(acc[j] * inv);
  *(u16x8*)(Mo + (size_t)node * 512 + c0) = o;
}

// ---------------- weight cast+transpose: WT[n][k] = bf16(W[k][n]), 512x512 ----------------
__global__ __launch_bounds__(256) void wcast_t(const float* __restrict__ W, u16* __restrict__ WT) {
  __shared__ u16 tile[64][72];
  const int k0 = blockIdx.y * 64, n0 = blockIdx.x * 64, t = threadIdx.x;
#pragma unroll
  for (int i = 0; i < 16; i++) {
    int kk = (t >> 6) * 16 + i, nn = t & 63;
    tile[nn][kk] = f2bf(W[(size_t)(k0 + kk) * 512 + n0 + nn]);
  }
  __syncthreads();
#pragma unroll
  for (int i = 0; i < 16; i++) {
    int nn = (t >> 6) * 16 + i, kk = t & 63;
    WT[(size_t)(n0 + nn) * 512 + k0 + kk] = tile[nn][kk];
  }
}

// ---------------- pooling: pooled[g] = mean rows of H2 graph block ----------------
__global__ __launch_bounds__(256) void pool_k(const u16* __restrict__ H2, float* __restrict__ pooled) {
  const int g = blockIdx.y, chunk = blockIdx.x, t = threadIdx.x;
  float s0 = 0.f, s1 = 0.f;
  const int r0 = chunk * 128;
  for (int r = r0; r < r0 + 128; r++) {
    const u16* row = H2 + ((size_t)(g << 10) + r) * 512;
    s0 += bf2f(row[t]);
    s1 += bf2f(row[t + 256]);
  }
  atomicAdd(&pooled[g * 512 + t], s0 * (1.0f / 1024.0f));
  atomicAdd(&pooled[g * 512 + t + 256], s1 * (1.0f / 1024.0f));
}

// ---------------- field = pooled @ gc_wr + gc_br  (fp32, tiny) ----------------
__global__ __launch_bounds__(256) void field_k(const float* __restrict__ pooled, const float* __restrict__ wr,
                                               const float* __restrict__ br, float* __restrict__ field) {
  int id = blockIdx.x * 256 + threadIdx.x;  // 32*512
  int g = id >> 9, j = id & 511;
  float s = br[j];
  for (int k = 0; k < 512; k++) s = fmaf(pooled[g * 512 + k], wr[k * 512 + j], s);
  field[id] = s;
}

// ---------------- final reduce: out = sum of 8 partial slices + bo2 ----------------
__global__ __launch_bounds__(256) void out_reduce(const float* __restrict__ part, const float* __restrict__ bo2,
                                                  float* __restrict__ out) {
  int id = blockIdx.x * 256 + threadIdx.x;  // NQ*3
  float s = bo2[id % 3];
#pragma unroll
  for (int sl = 0; sl < 8; sl++) s += part[(size_t)sl * NQVAL * 3 + id];
  out[id] = s;
}

// ---------------- GEMM: C = epilogue(A[M,512] @ BT[512,512]^T + bias) ----------------
// 128x128 tile, BK=32, 3-buffer 2-deep prefetch, counted vmcnt + raw s_barrier.
// MODE 0: C = relu(.) -> bf16       (GCN hidden layers)
// MODE 1: C = (.) * field[row>>13]  (trunk layer 2 fused with segment-broadcast mult)
// MODE 2: partial[slice] = (relu(.) @ wo2 over this 64-col wave slice)  (no atomics)
template <int MODE>
__global__ __launch_bounds__(256) void gemm_bt(const u16* __restrict__ A, const u16* __restrict__ BT,
                                               const float* __restrict__ bias, const float* __restrict__ field,
                                               const float* __restrict__ wo2, u16* __restrict__ C,
                                               float* __restrict__ outp, long rowoff) {
  constexpr int K = 512;
  constexpr int NT = 16;  // K / 32
  __shared__ u16 As[3][128 * 32];
  __shared__ u16 Bs[3][128 * 32];
  const int t = threadIdx.x;
  const int wave = t >> 6, lane = t & 63;
  const int wr = wave >> 1, wc = wave & 1;   // 2x2 wave grid, 64x64 out each
  const int lr = lane & 15, kg = lane >> 4;  // frag row, k-group
  const long m0 = (long)blockIdx.y * 128;
  const int n0 = blockIdx.x * 128;
  f32x4 acc[4][4] = {};
  // staging: linear LDS (byte t*16), per-lane global source
  const int ar = t >> 2, ac = (t & 3) * 8;
  const u16* gA0 = A + (m0 + ar) * K + ac;
  const u16* gA1 = gA0 + 64 * K;
  const u16* gB0 = BT + (long)(n0 + ar) * K + ac;
  const u16* gB1 = gB0 + 64 * K;

  auto STAGE = [&](int kt, int b) {
    gl2lds16(gA0 + kt, &As[b][t * 8]);
    gl2lds16(gA1 + kt, &As[b][2048 + t * 8]);
    gl2lds16(gB0 + kt, &Bs[b][t * 8]);
    gl2lds16(gB1 + kt, &Bs[b][2048 + t * 8]);
  };

  STAGE(0, 0);
  STAGE(32, 1);
  asm volatile("s_waitcnt vmcnt(4)" ::: "memory");  // tile 0 landed, tile 1 in flight
  __builtin_amdgcn_s_barrier();

#pragma unroll
  for (int tt = 0; tt < NT; ++tt) {
    const int b = tt % 3;
    if (tt + 2 < NT) STAGE((tt + 2) * 32, (tt + 2) % 3);
    bf16x8 af[4], bfv[4];
#pragma unroll
    for (int i = 0; i < 4; i++) {
      af[i]  = *(const bf16x8*)&As[b][(wr * 64 + i * 16 + lr) * 32 + kg * 8];
      bfv[i] = *(const bf16x8*)&Bs[b][(wc * 64 + i * 16 + lr) * 32 + kg * 8];
    }
#pragma unroll
    for (int mi = 0; mi < 4; mi++)
#pragma unroll
      for (int ni = 0; ni < 4; ni++)
        acc[mi][ni] = __builtin_amdgcn_mfma_f32_16x16x32_bf16(af[mi], bfv[ni], acc[mi][ni], 0, 0, 0);
    if (tt + 1 < NT) {
      if (tt + 2 < NT) asm volatile("s_waitcnt vmcnt(4)" ::: "memory");  // tile tt+1 landed
      else             asm volatile("s_waitcnt vmcnt(0)" ::: "memory");
      __builtin_amdgcn_s_barrier();
    }
  }

  if (MODE == 2) {
    // z2 = relu(acc + bo1); partial = z2 @ wo2 over this wave's 64 cols
    float po[4][4][3];
#pragma unroll
    for (int mi = 0; mi < 4; mi++)
#pragma unroll
      for (int r2 = 0; r2 < 4; r2++)
#pragma unroll
        for (int o = 0; o < 3; o++) po[mi][r2][o] = 0.0f;
#pragma unroll
    for (int ni = 0; ni < 4; ni++) {
      int col = n0 + wc * 64 + ni * 16 + lr;
      float bb = bias[col];
      float wa = wo2[col * 3 + 0], wb = wo2[col * 3 + 1], wcv = wo2[col * 3 + 2];
#pragma unroll
      for (int mi = 0; mi < 4; mi++)
#pragma unroll
        for (int r2 = 0; r2 < 4; r2++) {
          float v = fmaxf(acc[mi][ni][r2] + bb, 0.0f);
          po[mi][r2][0] = fmaf(v, wa, po[mi][r2][0]);
          po[mi][r2][1] = fmaf(v, wb, po[mi][r2][1]);
          po[mi][r2][2] = fmaf(v, wcv, po[mi][r2][2]);
        }
    }
#pragma unroll
    for (int s = 1; s < 16; s <<= 1)
#pragma unroll
      for (int mi = 0; mi < 4; mi++)
#pragma unroll
        for (int r2 = 0; r2 < 4; r2++)
#pragma unroll
          for (int o = 0; o < 3; o++) po[mi][r2][o] += __shfl_xor(po[mi][r2][o], s, 64);
    if (lr == 0) {
      const int slice = blockIdx.x * 2 + wc;
#pragma unroll
      for (int mi = 0; mi < 4; mi++)
#pragma unroll
        for (int r2 = 0; r2 < 4; r2++) {
          long grow = rowoff + m0 + wr * 64 + mi * 16 + kg * 4 + r2;
          float* p = outp + ((size_t)slice * NQVAL + grow) * 3;
          p[0] = po[mi][r2][0];
          p[1] = po[mi][r2][1];
          p[2] = po[mi][r2][2];
        }
    }
  } else {
    const int gq = (int)(m0 >> 13);  // 8192 query rows per graph
#pragma unroll
    for (int mi = 0; mi < 4; mi++)
#pragma unroll
      for (int ni = 0; ni < 4; ni++) {
        int col = n0 + wc * 64 + ni * 16 + lr;
        float bb = bias[col];
        float fm = (MODE == 1) ? field[gq * 512 + col] : 0.0f;
#pragma unroll
        for (int r2 = 0; r2 < 4; r2++) {
          long row = m0 + wr * 64 + mi * 16 + kg * 4 + r2;
          float v = acc[mi][ni][r2] + bb;
          v = (MODE == 1) ? v * fm : fmaxf(v, 0.0f);
          C[row * 512 + col] = f2bf(v);
        }
      }
  }
}

extern "C" void kernel_launch(void* const* d_in, const int* in_sizes, int n_in,
                              void* d_out, int out_size, void* d_ws, size_t ws_size,
                              hipStream_t stream) {
  const float* known = (const float*)d_in[0];
  const float* nodes = (const float*)d_in[1];
  const int* esrc = (const int*)d_in[2];
  const int* edst = (const int*)d_in[3];
  const float* gc_w0 = (const float*)d_in[6];
  const float* gc_b0 = (const float*)d_in[7];
  const float* gc_w1 = (const float*)d_in[8];
  const float* gc_b1 = (const float*)d_in[9];
  const float* gc_w2 = (const float*)d_in[10];
  const float* gc_b2 = (const float*)d_in[11];
  const float* gc_wr = (const float*)d_in[12];
  const float* gc_br = (const float*)d_in[13];
  const float* wt1 = (const float*)d_in[14];
  const float* bt1 = (const float*)d_in[15];
  const float* wt2 = (const float*)d_in[16];
  const float* bt2 = (const float*)d_in[17];
  const float* wo1 = (const float*)d_in[18];
  const float* bo1 = (const float*)d_in[19];
  const float* wo2 = (const float*)d_in[20];
  const float* bo2 = (const float*)d_in[21];
  float* out = (float*)d_out;
  (void)in_sizes; (void)n_in; (void)out_size;

  char* ws = (char*)d_ws;
  size_t off_b = 0;
  auto alloc = [&](size_t n) -> void* {
    void* p = ws + off_b;
    off_b += (n + 255) & ~(size_t)255;
    return p;
  };
  u16* w1T  = (u16*)alloc(512 * 512 * 2);
  u16* w2T  = (u16*)alloc(512 * 512 * 2);
  u16* wt2T = (u16*)alloc(512 * 512 * 2);
  u16* wo1T = (u16*)alloc(512 * 512 * 2);
  int* cnt   = (int*)alloc(NKVAL * 4);
  int* off   = (int*)alloc((NKVAL + 1) * 4);
  int* cur   = (int*)alloc(NKVAL * 4);
  int* srcs  = (int*)alloc((size_t)EVAL * 4);
  float* m0     = (float*)alloc(NKVAL * 3 * 4);
  float* pooled = (float*)alloc(32 * 512 * 4);
  float* field  = (float*)alloc(32 * 512 * 4);
  u16* bufA = (u16*)alloc((size_t)NKVAL * 512 * 2);  // also aliased as outpart (25.2MB <= 32MB)
  u16* bufB = (u16*)alloc((size_t)NKVAL * 512 * 2);
  u16* bufC = (u16*)alloc((size_t)NKVAL * 512 * 2);
  float* outpart = (float*)bufA;  // 8 slices x NQ x 3 f32, GCN phase done before query phase

  // adaptive chunking for the query path (t1c/zc: chunk_rows*1KB each)
  size_t rem = (ws_size > off_b) ? ws_size - off_b : 0;
  int chunk_rows = 32768;  // guaranteed-fit floor (prior rounds ran at ~165MB total)
  if ((size_t)262144 * 1024 * 2 <= rem) chunk_rows = 262144;
  else if ((size_t)131072 * 1024 * 2 <= rem) chunk_rows = 131072;
  else if ((size_t)65536 * 1024 * 2 <= rem) chunk_rows = 65536;
  u16* t1c = (u16*)alloc((size_t)chunk_rows * 512 * 2);
  u16* zc  = (u16*)alloc((size_t)chunk_rows * 512 * 2);
  const int nch = NQVAL / chunk_rows;

  hipMemsetAsync(cnt, 0, NKVAL * 4, stream);
  hipMemsetAsync(cur, 0, NKVAL * 4, stream);
  hipMemsetAsync(pooled, 0, 32 * 512 * 4, stream);

  wcast_t<<<dim3(8, 8), 256, 0, stream>>>(gc_w1, w1T);
  wcast_t<<<dim3(8, 8), 256, 0, stream>>>(gc_w2, w2T);
  wcast_t<<<dim3(8, 8), 256, 0, stream>>>(wt2, wt2T);
  wcast_t<<<dim3(8, 8), 256, 0, stream>>>(wo1, wo1T);

  degcnt_k<<<EVAL / 256, 256, 0, stream>>>(edst, cnt);
  scan_k<<<1, 1024, 0, stream>>>(cnt, off);
  scatter_k<<<EVAL / 256, 256, 0, stream>>>(esrc, edst, off, cur, srcs);
  agg0_csr<<<NKVAL / 256, 256, 0, stream>>>(off, srcs, known, m0);

  // h0 = relu((m0/deg) @ gc_w0 + b0)
  k3_dense<<<NKVAL * 64 / 256, 256, 0, stream>>>(m0, cnt, gc_w0, gc_b0, bufA, NKVAL);
  // m1 = segsum(h0[src])/deg  (CSR gather)
  agg_csr<<<NKVAL / 4, 256, 0, stream>>>(bufA, off, srcs, bufB);
  // h1 = relu(m1 @ W1 + b1)
  gemm_bt<0><<<dim3(4, NKVAL / 128), 256, 0, stream>>>(bufB, w1T, gc_b1, nullptr, nullptr, bufC, nullptr, 0);
  // m2
  agg_csr<<<NKVAL / 4, 256, 0, stream>>>(bufC, off, srcs, bufA);
  // h2
  gemm_bt<0><<<dim3(4, NKVAL / 128), 256, 0, stream>>>(bufA, w2T, gc_b2, nullptr, nullptr, bufB, nullptr, 0);
  pool_k<<<dim3(8, 32), 256, 0, stream>>>(bufB, pooled);
  field_k<<<64, 256, 0, stream>>>(pooled, gc_wr, gc_br, field);

  for (int ch = 0; ch < nch; ch++) {
    long rowoff = (long)ch * chunk_rows;
    // t1 = relu(nodes @ wt1 + bt1)
    k3_dense<<<chunk_rows * 64 / 256, 256, 0, stream>>>(nodes + rowoff * 3, nullptr, wt1, bt1, t1c, chunk_rows);
    // z = (t1 @ wt2 + bt2) * field[seg]
    gemm_bt<1><<<dim3(4, chunk_rows / 128), 256, 0, stream>>>(t1c, wt2T, bt2, field + (rowoff >> 13) * 512,
                                                              nullptr, zc, nullptr, 0);
    // partial[slice] = relu(z @ wo1 + bo1) @ wo2   (per n-block/wave-col slice, no atomics)
    gemm_bt<2><<<dim3(4, chunk_rows / 128), 256, 0, stream>>>(zc, wo1T, bo1, nullptr, wo2, nullptr,
                                                              outpart, rowoff);
  }
  // out = sum of 8 slices + bo2
  out_reduce<<<NQVAL * 3 / 256, 256, 0, stream>>>(outpart, bo2, out);
}

// Round 4
// 912.893 us; speedup vs baseline: 4.3871x; 1.0680x over previous
//
#include <hip/hip_runtime.h>

typedef unsigned short u16;
using u16x8  = __attribute__((ext_vector_type(8))) unsigned short;
using bf16x8 = __attribute__((ext_vector_type(8))) __bf16;
using f32x4  = __attribute__((ext_vector_type(4))) float;

#define NKVAL 32768
#define NQVAL 262144
#define EVAL  524288

__device__ __forceinline__ u16 f2bf(float f) {
  unsigned u = __float_as_uint(f);
  u = (u + 0x7fffu + ((u >> 16) & 1u)) >> 16;   // RNE
  return (u16)u;
}
__device__ __forceinline__ float bf2f(u16 h) {
  return __uint_as_float(((unsigned)h) << 16);
}
__device__ __forceinline__ void gl2lds16(const u16* g, u16* l) {
  __builtin_amdgcn_global_load_lds((const __attribute__((address_space(1))) void*)g,
                                   (__attribute__((address_space(3))) void*)l, 16, 0, 0);
}

// ---------------- int degree ----------------
__global__ __launch_bounds__(256) void degcnt_k(const int* __restrict__ dst, int* __restrict__ cnt) {
  int e = blockIdx.x * 256 + threadIdx.x;
  if (e < EVAL) atomicAdd(&cnt[dst[e]], 1);
}

// ---------------- exclusive scan over cnt[NKVAL] -> off[NKVAL+1], single block ----------------
__global__ __launch_bounds__(1024) void scan_k(const int* __restrict__ cnt, int* __restrict__ off) {
  __shared__ int part[1024];
  const int t = threadIdx.x;
  const int base = t * 32;
  int local[32];
  int s = 0;
#pragma unroll
  for (int i = 0; i < 32; i++) { local[i] = s; s += cnt[base + i]; }
  part[t] = s;
  __syncthreads();
  for (int d = 1; d < 1024; d <<= 1) {
    int v = (t >= d) ? part[t - d] : 0;
    __syncthreads();
    part[t] += v;
    __syncthreads();
  }
  int pre = (t == 0) ? 0 : part[t - 1];
#pragma unroll
  for (int i = 0; i < 32; i++) off[base + i] = pre + local[i];
  if (t == 1023) off[NKVAL] = pre + s;
}

// ---------------- scatter edges into CSR-by-dst ----------------
__global__ __launch_bounds__(256) void scatter_k(const int* __restrict__ src, const int* __restrict__ dst,
                                                 const int* __restrict__ off, int* __restrict__ cur,
                                                 int* __restrict__ srcs_sorted) {
  int e = blockIdx.x * 256 + threadIdx.x;
  if (e < EVAL) {
    int d = dst[e];
    int p = atomicAdd(&cur[d], 1);
    srcs_sorted[off[d] + p] = src[e];
  }
}

// ---------------- layer-0 aggregation via CSR (no atomics) ----------------
__global__ __launch_bounds__(256) void agg0_csr(const int* __restrict__ off, const int* __restrict__ srcs,
                                                const float* __restrict__ known, float* __restrict__ m0) {
  int d = blockIdx.x * 256 + threadIdx.x;
  if (d >= NKVAL) return;
  int b = off[d], e = off[d + 1];
  float a0 = 0.f, a1 = 0.f, a2 = 0.f;
  for (int i = b; i < e; i++) {
    int s = srcs[i];
    a0 += known[s * 3 + 0];
    a1 += known[s * 3 + 1];
    a2 += known[s * 3 + 2];
  }
  m0[d * 3 + 0] = a0;
  m0[d * 3 + 1] = a1;
  m0[d * 3 + 2] = a2;
}

// ---------------- K=3 dense: Y = relu((X[/cnt]) @ W[3,512] + b) -> bf16, vectorized ----------------
__global__ __launch_bounds__(256) void k3_dense(const float* __restrict__ X, const int* __restrict__ cnt,
                                                const float* __restrict__ W, const float* __restrict__ Bb,
                                                u16* __restrict__ Y, int M) {
  int id = blockIdx.x * 256 + threadIdx.x;  // M*64 threads, 8 outputs each
  if (id >= M * 64) return;
  int i = id >> 6, j0 = (id & 63) * 8;
  float x0 = X[i * 3 + 0], x1 = X[i * 3 + 1], x2 = X[i * 3 + 2];
  if (cnt) {
    float inv = 1.0f / fmaxf((float)cnt[i], 1.0f);
    x0 *= inv; x1 *= inv; x2 *= inv;
  }
  u16x8 o;
#pragma unroll
  for (int j = 0; j < 8; j++) {
    float v = fmaf(x0, W[j0 + j], Bb[j0 + j]);
    v = fmaf(x1, W[512 + j0 + j], v);
    v = fmaf(x2, W[1024 + j0 + j], v);
    o[j] = f2bf(fmaxf(v, 0.0f));
  }
  *(u16x8*)(Y + (size_t)i * 512 + j0) = o;
}

// ---------------- GCN aggregation via CSR: wave per dst node, regs only ----------------
// XCD-locality swizzle: XCD c (blockIdx%8) handles nodes [c*4096,(c+1)*4096) -> 4 graphs
// = 4MB of H per XCD L2 (grid 8192 % 8 == 0 -> bijective).
__global__ __launch_bounds__(256) void agg_csr(const u16* __restrict__ H, const int* __restrict__ off,
                                               const int* __restrict__ srcs, u16* __restrict__ Mo) {
  const int raw = blockIdx.x;
  const int nb = (raw & 7) * 1024 + (raw >> 3);
  const int node = nb * 4 + (threadIdx.x >> 6);
  const int lane = threadIdx.x & 63;
  const int beg = off[node], end = off[node + 1];
  const int c0 = lane * 8;
  float acc[8] = {0, 0, 0, 0, 0, 0, 0, 0};
  int e = beg;
  for (; e + 4 <= end; e += 4) {
    int s0 = srcs[e], s1 = srcs[e + 1], s2 = srcs[e + 2], s3 = srcs[e + 3];
    u16x8 h0 = *(const u16x8*)(H + (size_t)s0 * 512 + c0);
    u16x8 h1 = *(const u16x8*)(H + (size_t)s1 * 512 + c0);
    u16x8 h2 = *(const u16x8*)(H + (size_t)s2 * 512 + c0);
    u16x8 h3 = *(const u16x8*)(H + (size_t)s3 * 512 + c0);
#pragma unroll
    for (int j = 0; j < 8; j++)
      acc[j] += (bf2f(h0[j]) + bf2f(h1[j])) + (bf2f(h2[j]) + bf2f(h3[j]));
  }
  for (; e < end; e++) {
    int s = srcs[e];
    u16x8 hv = *(const u16x8*)(H + (size_t)s * 512 + c0);
#pragma unroll
    for (int j = 0; j < 8; j++) acc[j] += bf2f(hv[j]);
  }
  float inv = 1.0f / fmaxf((float)(end - beg), 1.0f);
  u16x8 o;
#pragma unroll
  for (int j = 0; j < 8; j++) o[j] = f2bf(acc[j] * inv);
  *(u16x8*)(Mo + (size_t)node * 512 + c0) = o;
}

// ---------------- weight cast+transpose: WT[n][k] = bf16(W[k][n]), 512x512 ----------------
__global__ __launch_bounds__(256) void wcast_t(const float* __restrict__ W, u16* __restrict__ WT) {
  __shared__ u16 tile[64][72];
  const int k0 = blockIdx.y * 64, n0 = blockIdx.x * 64, t = threadIdx.x;
#pragma unroll
  for (int i = 0; i < 16; i++) {
    int kk = (t >> 6) * 16 + i, nn = t & 63;
    tile[nn][kk] = f2bf(W[(size_t)(k0 + kk) * 512 + n0 + nn]);
  }
  __syncthreads();
#pragma unroll
  for (int i = 0; i < 16; i++) {
    int nn = (t >> 6) * 16 + i, kk = t & 63;
    WT[(size_t)(n0 + nn) * 512 + k0 + kk] = tile[nn][kk];
  }
}

// ---------------- pooling: pooled[g] = mean rows of H2 graph block ----------------
__global__ __launch_bounds__(256) void pool_k(const u16* __restrict__ H2, float* __restrict__ pooled) {
  const int g = blockIdx.y, chunk = blockIdx.x, t = threadIdx.x;
  float s0 = 0.f, s1 = 0.f;
  const int r0 = chunk * 128;
  for (int r = r0; r < r0 + 128; r++) {
    const u16* row = H2 + ((size_t)(g << 10) + r) * 512;
    s0 += bf2f(row[t]);
    s1 += bf2f(row[t + 256]);
  }
  atomicAdd(&pooled[g * 512 + t], s0 * (1.0f / 1024.0f));
  atomicAdd(&pooled[g * 512 + t + 256], s1 * (1.0f / 1024.0f));
}

// ---------------- field = pooled @ gc_wr + gc_br  (fp32, tiny) ----------------
__global__ __launch_bounds__(256) void field_k(const float* __restrict__ pooled, const float* __restrict__ wr,
                                               const float* __restrict__ br, float* __restrict__ field) {
  int id = blockIdx.x * 256 + threadIdx.x;  // 32*512
  int g = id >> 9, j = id & 511;
  float s = br[j];
  for (int k = 0; k < 512; k++) s = fmaf(pooled[g * 512 + k], wr[k * 512 + j], s);
  field[id] = s;
}

// ---------------- final reduce: out = sum of 8 partial slices + bo2 ----------------
__global__ __launch_bounds__(256) void out_reduce(const float* __restrict__ part, const float* __restrict__ bo2,
                                                  float* __restrict__ out) {
  int id = blockIdx.x * 256 + threadIdx.x;  // NQ*3
  float s = bo2[id % 3];
#pragma unroll
  for (int sl = 0; sl < 8; sl++) s += part[(size_t)sl * NQVAL * 3 + id];
  out[id] = s;
}

// ---------------- GEMM: C = epilogue(A[M,512] @ BT[512,512]^T + bias) ----------------
// 128x128 tile, BK=32, 3-buffer 2-deep prefetch, counted vmcnt + raw s_barrier.
// MODE 0: A from memory; C = relu(.) -> bf16            (GCN hidden layers)
// MODE 1: A = relu(nodes@wt1+bt1) computed in staging;  C = (.) * field[row>>13]
// MODE 2: A from memory; partial[slice] = relu(.) @ wo2 (no atomics)
template <int MODE>
__global__ __launch_bounds__(256) void gemm_bt(const u16* __restrict__ A, const u16* __restrict__ BT,
                                               const float* __restrict__ bias, const float* __restrict__ field,
                                               const float* __restrict__ wo2, u16* __restrict__ C,
                                               float* __restrict__ outp, long rowoff,
                                               const float* __restrict__ nodes3,
                                               const float* __restrict__ wt1,
                                               const float* __restrict__ bt1) {
  constexpr int K = 512;
  constexpr int NT = 16;  // K / 32
  __shared__ u16 As[3][128 * 32];
  __shared__ u16 Bs[3][128 * 32];
  const int t = threadIdx.x;
  const int wave = t >> 6, lane = t & 63;
  const int wr = wave >> 1, wc = wave & 1;   // 2x2 wave grid, 64x64 out each
  const int lr = lane & 15, kg = lane >> 4;  // frag row, k-group
  const long m0 = (long)blockIdx.y * 128;
  const int n0 = blockIdx.x * 128;
  f32x4 acc[4][4] = {};
  // staging: linear LDS (byte t*16), per-lane global source
  const int ar = t >> 2, ac = (t & 3) * 8;
  const u16* gA0 = nullptr;
  const u16* gA1 = nullptr;
  if constexpr (MODE != 1) {
    gA0 = A + (m0 + ar) * K + ac;
    gA1 = gA0 + 64 * K;
  }
  const u16* gB0 = BT + (long)(n0 + ar) * K + ac;
  const u16* gB1 = gB0 + 64 * K;
  // trunk-1 fused inputs (MODE 1 only)
  float n0x = 0, n0y = 0, n0z = 0, n1x = 0, n1y = 0, n1z = 0;
  if constexpr (MODE == 1) {
    const float* nr0 = nodes3 + (m0 + ar) * 3;
    const float* nr1 = nodes3 + (m0 + ar + 64) * 3;
    n0x = nr0[0]; n0y = nr0[1]; n0z = nr0[2];
    n1x = nr1[0]; n1y = nr1[1]; n1z = nr1[2];
  }

  auto STAGE = [&](int kt, int b) {
    if constexpr (MODE == 1) {
      // A-tile computed: relu(nodes @ wt1[:, kt+ac .. +8] + bt1)
      float w0[8], w1[8], w2[8], bb[8];
      const float* wp = wt1 + kt + ac;
      *(float4*)&w0[0] = *(const float4*)(wp);
      *(float4*)&w0[4] = *(const float4*)(wp + 4);
      *(float4*)&w1[0] = *(const float4*)(wp + 512);
      *(float4*)&w1[4] = *(const float4*)(wp + 516);
      *(float4*)&w2[0] = *(const float4*)(wp + 1024);
      *(float4*)&w2[4] = *(const float4*)(wp + 1028);
      *(float4*)&bb[0] = *(const float4*)(bt1 + kt + ac);
      *(float4*)&bb[4] = *(const float4*)(bt1 + kt + ac + 4);
      u16x8 o0, o1;
#pragma unroll
      for (int j = 0; j < 8; j++) {
        float v0 = fmaf(n0x, w0[j], fmaf(n0y, w1[j], fmaf(n0z, w2[j], bb[j])));
        float v1 = fmaf(n1x, w0[j], fmaf(n1y, w1[j], fmaf(n1z, w2[j], bb[j])));
        o0[j] = f2bf(fmaxf(v0, 0.0f));
        o1[j] = f2bf(fmaxf(v1, 0.0f));
      }
      *(u16x8*)&As[b][t * 8] = o0;
      *(u16x8*)&As[b][2048 + t * 8] = o1;
    } else {
      gl2lds16(gA0 + kt, &As[b][t * 8]);
      gl2lds16(gA1 + kt, &As[b][2048 + t * 8]);
    }
    gl2lds16(gB0 + kt, &Bs[b][t * 8]);
    gl2lds16(gB1 + kt, &Bs[b][2048 + t * 8]);
  };

  STAGE(0, 0);
  STAGE(32, 1);
  if constexpr (MODE == 1) asm volatile("s_waitcnt vmcnt(2) lgkmcnt(0)" ::: "memory");
  else                     asm volatile("s_waitcnt vmcnt(4) lgkmcnt(0)" ::: "memory");
  __builtin_amdgcn_s_barrier();

#pragma unroll
  for (int tt = 0; tt < NT; ++tt) {
    const int b = tt % 3;
    if (tt + 2 < NT) STAGE((tt + 2) * 32, (tt + 2) % 3);
    bf16x8 af[4], bfv[4];
#pragma unroll
    for (int i = 0; i < 4; i++) {
      af[i]  = *(const bf16x8*)&As[b][(wr * 64 + i * 16 + lr) * 32 + kg * 8];
      bfv[i] = *(const bf16x8*)&Bs[b][(wc * 64 + i * 16 + lr) * 32 + kg * 8];
    }
#pragma unroll
    for (int mi = 0; mi < 4; mi++)
#pragma unroll
      for (int ni = 0; ni < 4; ni++)
        acc[mi][ni] = __builtin_amdgcn_mfma_f32_16x16x32_bf16(af[mi], bfv[ni], acc[mi][ni], 0, 0, 0);
    if (tt + 1 < NT) {
      if (tt + 2 < NT) {
        if constexpr (MODE == 1) asm volatile("s_waitcnt vmcnt(2) lgkmcnt(0)" ::: "memory");
        else                     asm volatile("s_waitcnt vmcnt(4) lgkmcnt(0)" ::: "memory");
      } else {
        asm volatile("s_waitcnt vmcnt(0) lgkmcnt(0)" ::: "memory");
      }
      __builtin_amdgcn_s_barrier();
    }
  }

  if (MODE == 2) {
    // z2 = relu(acc + bo1); partial = z2 @ wo2 over this wave's 64 cols
    float po[4][4][3];
#pragma unroll
    for (int mi = 0; mi < 4; mi++)
#pragma unroll
      for (int r2 = 0; r2 < 4; r2++)
#pragma unroll
        for (int o = 0; o < 3; o++) po[mi][r2][o] = 0.0f;
#pragma unroll
    for (int ni = 0; ni < 4; ni++) {
      int col = n0 + wc * 64 + ni * 16 + lr;
      float bb = bias[col];
      float wa = wo2[col * 3 + 0], wb = wo2[col * 3 + 1], wcv = wo2[col * 3 + 2];
#pragma unroll
      for (int mi = 0; mi < 4; mi++)
#pragma unroll
        for (int r2 = 0; r2 < 4; r2++) {
          float v = fmaxf(acc[mi][ni][r2] + bb, 0.0f);
          po[mi][r2][0] = fmaf(v, wa, po[mi][r2][0]);
          po[mi][r2][1] = fmaf(v, wb, po[mi][r2][1]);
          po[mi][r2][2] = fmaf(v, wcv, po[mi][r2][2]);
        }
    }
#pragma unroll
    for (int s = 1; s < 16; s <<= 1)
#pragma unroll
      for (int mi = 0; mi < 4; mi++)
#pragma unroll
        for (int r2 = 0; r2 < 4; r2++)
#pragma unroll
          for (int o = 0; o < 3; o++) po[mi][r2][o] += __shfl_xor(po[mi][r2][o], s, 64);
    if (lr == 0) {
      const int slice = blockIdx.x * 2 + wc;
#pragma unroll
      for (int mi = 0; mi < 4; mi++)
#pragma unroll
        for (int r2 = 0; r2 < 4; r2++) {
          long grow = rowoff + m0 + wr * 64 + mi * 16 + kg * 4 + r2;
          float* p = outp + ((size_t)slice * NQVAL + grow) * 3;
          p[0] = po[mi][r2][0];
          p[1] = po[mi][r2][1];
          p[2] = po[mi][r2][2];
        }
    }
  } else {
    const int gq = (int)(m0 >> 13);  // 8192 query rows per graph
#pragma unroll
    for (int mi = 0; mi < 4; mi++)
#pragma unroll
      for (int ni = 0; ni < 4; ni++) {
        int col = n0 + wc * 64 + ni * 16 + lr;
        float bb = bias[col];
        float fm = (MODE == 1) ? field[gq * 512 + col] : 0.0f;
#pragma unroll
        for (int r2 = 0; r2 < 4; r2++) {
          long row = m0 + wr * 64 + mi * 16 + kg * 4 + r2;
          float v = acc[mi][ni][r2] + bb;
          v = (MODE == 1) ? v * fm : fmaxf(v, 0.0f);
          C[row * 512 + col] = f2bf(v);
        }
      }
  }
}

extern "C" void kernel_launch(void* const* d_in, const int* in_sizes, int n_in,
                              void* d_out, int out_size, void* d_ws, size_t ws_size,
                              hipStream_t stream) {
  const float* known = (const float*)d_in[0];
  const float* nodes = (const float*)d_in[1];
  const int* esrc = (const int*)d_in[2];
  const int* edst = (const int*)d_in[3];
  const float* gc_w0 = (const float*)d_in[6];
  const float* gc_b0 = (const float*)d_in[7];
  const float* gc_w1 = (const float*)d_in[8];
  const float* gc_b1 = (const float*)d_in[9];
  const float* gc_w2 = (const float*)d_in[10];
  const float* gc_b2 = (const float*)d_in[11];
  const float* gc_wr = (const float*)d_in[12];
  const float* gc_br = (const float*)d_in[13];
  const float* wt1 = (const float*)d_in[14];
  const float* bt1 = (const float*)d_in[15];
  const float* wt2 = (const float*)d_in[16];
  const float* bt2 = (const float*)d_in[17];
  const float* wo1 = (const float*)d_in[18];
  const float* bo1 = (const float*)d_in[19];
  const float* wo2 = (const float*)d_in[20];
  const float* bo2 = (const float*)d_in[21];
  float* out = (float*)d_out;
  (void)in_sizes; (void)n_in; (void)out_size;

  char* ws = (char*)d_ws;
  size_t off_b = 0;
  auto alloc = [&](size_t n) -> void* {
    void* p = ws + off_b;
    off_b += (n + 255) & ~(size_t)255;
    return p;
  };
  u16* w1T  = (u16*)alloc(512 * 512 * 2);
  u16* w2T  = (u16*)alloc(512 * 512 * 2);
  u16* wt2T = (u16*)alloc(512 * 512 * 2);
  u16* wo1T = (u16*)alloc(512 * 512 * 2);
  int* cnt   = (int*)alloc(NKVAL * 4);
  int* off   = (int*)alloc((NKVAL + 1) * 4);
  int* cur   = (int*)alloc(NKVAL * 4);
  int* srcs  = (int*)alloc((size_t)EVAL * 4);
  float* m0     = (float*)alloc(NKVAL * 3 * 4);
  float* pooled = (float*)alloc(32 * 512 * 4);
  float* field  = (float*)alloc(32 * 512 * 4);
  u16* bufA = (u16*)alloc((size_t)NKVAL * 512 * 2);  // aliased as outpart in query phase
  u16* bufB = (u16*)alloc((size_t)NKVAL * 512 * 2);
  u16* bufC = (u16*)alloc((size_t)NKVAL * 512 * 2);
  float* outpart = (float*)bufA;  // 8 slices x NQ x 3 f32 = 25.2MB <= 32MB

  // adaptive chunking for the query path (zc: chunk_rows KB)
  size_t rem = (ws_size > off_b) ? ws_size - off_b : 0;
  int chunk_rows = 32768;
  if ((size_t)262144 * 1024 <= rem) chunk_rows = 262144;
  else if ((size_t)131072 * 1024 <= rem) chunk_rows = 131072;
  else if ((size_t)65536 * 1024 <= rem) chunk_rows = 65536;
  u16* zc = (u16*)alloc((size_t)chunk_rows * 512 * 2);
  const int nch = NQVAL / chunk_rows;

  hipMemsetAsync(cnt, 0, NKVAL * 4, stream);
  hipMemsetAsync(cur, 0, NKVAL * 4, stream);
  hipMemsetAsync(pooled, 0, 32 * 512 * 4, stream);

  wcast_t<<<dim3(8, 8), 256, 0, stream>>>(gc_w1, w1T);
  wcast_t<<<dim3(8, 8), 256, 0, stream>>>(gc_w2, w2T);
  wcast_t<<<dim3(8, 8), 256, 0, stream>>>(wt2, wt2T);
  wcast_t<<<dim3(8, 8), 256, 0, stream>>>(wo1, wo1T);

  degcnt_k<<<EVAL / 256, 256, 0, stream>>>(edst, cnt);
  scan_k<<<1, 1024, 0, stream>>>(cnt, off);
  scatter_k<<<EVAL / 256, 256, 0, stream>>>(esrc, edst, off, cur, srcs);
  agg0_csr<<<NKVAL / 256, 256, 0, stream>>>(off, srcs, known, m0);

  // h0 = relu((m0/deg) @ gc_w0 + b0)
  k3_dense<<<NKVAL * 64 / 256, 256, 0, stream>>>(m0, cnt, gc_w0, gc_b0, bufA, NKVAL);
  // m1 = segsum(h0[src])/deg  (CSR gather, XCD-local)
  agg_csr<<<NKVAL / 4, 256, 0, stream>>>(bufA, off, srcs, bufB);
  // h1 = relu(m1 @ W1 + b1)
  gemm_bt<0><<<dim3(4, NKVAL / 128), 256, 0, stream>>>(bufB, w1T, gc_b1, nullptr, nullptr, bufC, nullptr, 0,
                                                       nullptr, nullptr, nullptr);
  // m2
  agg_csr<<<NKVAL / 4, 256, 0, stream>>>(bufC, off, srcs, bufA);
  // h2
  gemm_bt<0><<<dim3(4, NKVAL / 128), 256, 0, stream>>>(bufA, w2T, gc_b2, nullptr, nullptr, bufB, nullptr, 0,
                                                       nullptr, nullptr, nullptr);
  pool_k<<<dim3(8, 32), 256, 0, stream>>>(bufB, pooled);
  field_k<<<64, 256, 0, stream>>>(pooled, gc_wr, gc_br, field);

  for (int ch = 0; ch < nch; ch++) {
    long rowoff = (long)ch * chunk_rows;
    // z = (relu(nodes@wt1+bt1) @ wt2 + bt2) * field[seg]   (trunk-1 fused into staging)
    gemm_bt<1><<<dim3(4, chunk_rows / 128), 256, 0, stream>>>(nullptr, wt2T, bt2,
                                                              field + (rowoff >> 13) * 512, nullptr, zc, nullptr, 0,
                                                              nodes + rowoff * 3, wt1, bt1);
    // partial[slice] = relu(z @ wo1 + bo1) @ wo2   (per n-block/wave-col slice, no atomics)
    gemm_bt<2><<<dim3(4, chunk_rows / 128), 256, 0, stream>>>(zc, wo1T, bo1, nullptr, wo2, nullptr,
                                                              outpart, rowoff, nullptr, nullptr, nullptr);
  }
  // out = sum of 8 slices + bo2
  out_reduce<<<NQVAL * 3 / 256, 256, 0, stream>>>(outpart, bo2, out);
}

// Round 5
// 900.329 us; speedup vs baseline: 4.4483x; 1.0140x over previous
//
#include <hip/hip_runtime.h>

typedef unsigned short u16;
using u16x8  = __attribute__((ext_vector_type(8))) unsigned short;
using bf16x8 = __attribute__((ext_vector_type(8))) __bf16;
using f32x4  = __attribute__((ext_vector_type(4))) float;

#define NKVAL 32768
#define NQVAL 262144
#define EVAL  524288

__device__ __forceinline__ u16 f2bf(float f) {
  unsigned u = __float_as_uint(f);
  u = (u + 0x7fffu + ((u >> 16) & 1u)) >> 16;   // RNE
  return (u16)u;
}
__device__ __forceinline__ float bf2f(u16 h) {
  return __uint_as_float(((unsigned)h) << 16);
}
__device__ __forceinline__ void gl2lds16(const u16* g, u16* l) {
  __builtin_amdgcn_global_load_lds((const __attribute__((address_space(1))) void*)g,
                                   (__attribute__((address_space(3))) void*)l, 16, 0, 0);
}

// ---------------- int degree ----------------
__global__ __launch_bounds__(256) void degcnt_k(const int* __restrict__ dst, int* __restrict__ cnt) {
  int e = blockIdx.x * 256 + threadIdx.x;
  if (e < EVAL) atomicAdd(&cnt[dst[e]], 1);
}

// ---------------- exclusive scan over cnt[NKVAL] -> off[NKVAL+1], single block ----------------
__global__ __launch_bounds__(1024) void scan_k(const int* __restrict__ cnt, int* __restrict__ off) {
  __shared__ int part[1024];
  const int t = threadIdx.x;
  const int base = t * 32;
  int local[32];
  int s = 0;
#pragma unroll
  for (int i = 0; i < 32; i++) { local[i] = s; s += cnt[base + i]; }
  part[t] = s;
  __syncthreads();
  for (int d = 1; d < 1024; d <<= 1) {
    int v = (t >= d) ? part[t - d] : 0;
    __syncthreads();
    part[t] += v;
    __syncthreads();
  }
  int pre = (t == 0) ? 0 : part[t - 1];
#pragma unroll
  for (int i = 0; i < 32; i++) off[base + i] = pre + local[i];
  if (t == 1023) off[NKVAL] = pre + s;
}

// ---------------- scatter edges into CSR-by-dst ----------------
__global__ __launch_bounds__(256) void scatter_k(const int* __restrict__ src, const int* __restrict__ dst,
                                                 const int* __restrict__ off, int* __restrict__ cur,
                                                 int* __restrict__ srcs_sorted) {
  int e = blockIdx.x * 256 + threadIdx.x;
  if (e < EVAL) {
    int d = dst[e];
    int p = atomicAdd(&cur[d], 1);
    srcs_sorted[off[d] + p] = src[e];
  }
}

// ---------------- layer-0 aggregation via CSR (no atomics) ----------------
__global__ __launch_bounds__(256) void agg0_csr(const int* __restrict__ off, const int* __restrict__ srcs,
                                                const float* __restrict__ known, float* __restrict__ m0) {
  int d = blockIdx.x * 256 + threadIdx.x;
  if (d >= NKVAL) return;
  int b = off[d], e = off[d + 1];
  float a0 = 0.f, a1 = 0.f, a2 = 0.f;
  for (int i = b; i < e; i++) {
    int s = srcs[i];
    a0 += known[s * 3 + 0];
    a1 += known[s * 3 + 1];
    a2 += known[s * 3 + 2];
  }
  m0[d * 3 + 0] = a0;
  m0[d * 3 + 1] = a1;
  m0[d * 3 + 2] = a2;
}

// ---------------- K=3 dense: Y = relu((X[/cnt]) @ W[3,512] + b) -> bf16, vectorized ----------------
__global__ __launch_bounds__(256) void k3_dense(const float* __restrict__ X, const int* __restrict__ cnt,
                                                const float* __restrict__ W, const float* __restrict__ Bb,
                                                u16* __restrict__ Y, int M) {
  int id = blockIdx.x * 256 + threadIdx.x;  // M*64 threads, 8 outputs each
  if (id >= M * 64) return;
  int i = id >> 6, j0 = (id & 63) * 8;
  float x0 = X[i * 3 + 0], x1 = X[i * 3 + 1], x2 = X[i * 3 + 2];
  if (cnt) {
    float inv = 1.0f / fmaxf((float)cnt[i], 1.0f);
    x0 *= inv; x1 *= inv; x2 *= inv;
  }
  u16x8 o;
#pragma unroll
  for (int j = 0; j < 8; j++) {
    float v = fmaf(x0, W[j0 + j], Bb[j0 + j]);
    v = fmaf(x1, W[512 + j0 + j], v);
    v = fmaf(x2, W[1024 + j0 + j], v);
    o[j] = f2bf(fmaxf(v, 0.0f));
  }
  *(u16x8*)(Y + (size_t)i * 512 + j0) = o;
}

// ---------------- GCN aggregation via CSR: wave per dst node, regs only ----------------
// XCD-locality swizzle: XCD c (blockIdx%8) handles nodes [c*4096,(c+1)*4096) -> 4 graphs
// = 4MB of H per XCD L2 (grid 8192 % 8 == 0 -> bijective).
__global__ __launch_bounds__(256) void agg_csr(const u16* __restrict__ H, const int* __restrict__ off,
                                               const int* __restrict__ srcs, u16* __restrict__ Mo) {
  const int raw = blockIdx.x;
  const int nb = (raw & 7) * 1024 + (raw >> 3);
  const int node = nb * 4 + (threadIdx.x >> 6);
  const int lane = threadIdx.x & 63;
  const int beg = off[node], end = off[node + 1];
  const int c0 = lane * 8;
  float acc[8] = {0, 0, 0, 0, 0, 0, 0, 0};
  int e = beg;
  for (; e + 4 <= end; e += 4) {
    int s0 = srcs[e], s1 = srcs[e + 1], s2 = srcs[e + 2], s3 = srcs[e + 3];
    u16x8 h0 = *(const u16x8*)(H + (size_t)s0 * 512 + c0);
    u16x8 h1 = *(const u16x8*)(H + (size_t)s1 * 512 + c0);
    u16x8 h2 = *(const u16x8*)(H + (size_t)s2 * 512 + c0);
    u16x8 h3 = *(const u16x8*)(H + (size_t)s3 * 512 + c0);
#pragma unroll
    for (int j = 0; j < 8; j++)
      acc[j] += (bf2f(h0[j]) + bf2f(h1[j])) + (bf2f(h2[j]) + bf2f(h3[j]));
  }
  for (; e < end; e++) {
    int s = srcs[e];
    u16x8 hv = *(const u16x8*)(H + (size_t)s * 512 + c0);
#pragma unroll
    for (int j = 0; j < 8; j++) acc[j] += bf2f(hv[j]);
  }
  float inv = 1.0f / fmaxf((float)(end - beg), 1.0f);
  u16x8 o;
#pragma unroll
  for (int j = 0; j < 8; j++) o[j] = f2bf(acc[j] * inv);
  *(u16x8*)(Mo + (size_t)node * 512 + c0) = o;
}

// ---------------- weight cast+transpose: WT[n][k] = bf16(W[k][n]), 512x512 ----------------
__global__ __launch_bounds__(256) void wcast_t(const float* __restrict__ W, u16* __restrict__ WT) {
  __shared__ u16 tile[64][72];
  const int k0 = blockIdx.y * 64, n0 = blockIdx.x * 64, t = threadIdx.x;
#pragma unroll
  for (int i = 0; i < 16; i++) {
    int kk = (t >> 6) * 16 + i, nn = t & 63;
    tile[nn][kk] = f2bf(W[(size_t)(k0 + kk) * 512 + n0 + nn]);
  }
  __syncthreads();
#pragma unroll
  for (int i = 0; i < 16; i++) {
    int nn = (t >> 6) * 16 + i, kk = t & 63;
    WT[(size_t)(n0 + nn) * 512 + k0 + kk] = tile[nn][kk];
  }
}

// ---------------- pooling: pooled[g] = mean rows of H2 graph block ----------------
__global__ __launch_bounds__(256) void pool_k(const u16* __restrict__ H2, float* __restrict__ pooled) {
  const int g = blockIdx.y, chunk = blockIdx.x, t = threadIdx.x;
  float s0 = 0.f, s1 = 0.f;
  const int r0 = chunk * 128;
  for (int r = r0; r < r0 + 128; r++) {
    const u16* row = H2 + ((size_t)(g << 10) + r) * 512;
    s0 += bf2f(row[t]);
    s1 += bf2f(row[t + 256]);
  }
  atomicAdd(&pooled[g * 512 + t], s0 * (1.0f / 1024.0f));
  atomicAdd(&pooled[g * 512 + t + 256], s1 * (1.0f / 1024.0f));
}

// ---------------- field = pooled @ gc_wr + gc_br  (fp32, tiny) ----------------
__global__ __launch_bounds__(256) void field_k(const float* __restrict__ pooled, const float* __restrict__ wr,
                                               const float* __restrict__ br, float* __restrict__ field) {
  int id = blockIdx.x * 256 + threadIdx.x;  // 32*512
  int g = id >> 9, j = id & 511;
  float s = br[j];
  for (int k = 0; k < 512; k++) s = fmaf(pooled[g * 512 + k], wr[k * 512 + j], s);
  field[id] = s;
}

// ---------------- final reduce: out = sum of 8 partial slices + bo2 ----------------
__global__ __launch_bounds__(256) void out_reduce(const float* __restrict__ part, const float* __restrict__ bo2,
                                                  float* __restrict__ out) {
  int id = blockIdx.x * 256 + threadIdx.x;  // NQ*3
  float s = bo2[id % 3];
#pragma unroll
  for (int sl = 0; sl < 8; sl++) s += part[(size_t)sl * NQVAL * 3 + id];
  out[id] = s;
}

// ---------------- GEMM: C = epilogue(A[M,512] @ BT[512,512]^T + bias) ----------------
// 128x128 tile, BK=32, 3-buffer 2-deep prefetch, counted vmcnt + raw s_barrier.
// LDS XOR-swizzle (T2, rule #21): LDS[row][slot] holds A[row][slot ^ ((row>>1)&3)];
// gl2lds keeps a linear dest and the GLOBAL source col is pre-swizzled; the
// fragment ds_read XORs the slot, making each wave's 8 reads a contiguous 1KB
// (conflict-free) instead of an 8-way bank conflict.
// MODE 0: A from memory; C = relu(.) -> bf16            (GCN hidden layers)
// MODE 1: A = relu(nodes@wt1+bt1) computed in staging;  C = (.) * field[row>>13]
// MODE 2: A from memory; partial[slice] = relu(.) @ wo2 (no atomics)
template <int MODE>
__global__ __launch_bounds__(256) void gemm_bt(const u16* __restrict__ A, const u16* __restrict__ BT,
                                               const float* __restrict__ bias, const float* __restrict__ field,
                                               const float* __restrict__ wo2, u16* __restrict__ C,
                                               float* __restrict__ outp, long rowoff,
                                               const float* __restrict__ nodes3,
                                               const float* __restrict__ wt1,
                                               const float* __restrict__ bt1) {
  constexpr int K = 512;
  constexpr int NT = 16;  // K / 32
  __shared__ u16 As[3][128 * 32];
  __shared__ u16 Bs[3][128 * 32];
  const int t = threadIdx.x;
  const int wave = t >> 6, lane = t & 63;
  const int wr = wave >> 1, wc = wave & 1;   // 2x2 wave grid, 64x64 out each
  const int lr = lane & 15, kg = lane >> 4;  // frag row, k-group
  const int kx = (lr >> 1) & 3;              // read-side slot XOR key
  const long m0 = (long)blockIdx.y * 128;
  const int n0 = blockIdx.x * 128;
  f32x4 acc[4][4] = {};
  // staging: linear LDS (byte t*16), per-lane global source with pre-swizzled col
  const int ar = t >> 2;
  const int ac = (((t & 3) ^ ((t >> 3) & 3)) * 8);  // source col pre-swizzle
  const u16* gA0 = nullptr;
  const u16* gA1 = nullptr;
  if constexpr (MODE != 1) {
    gA0 = A + (m0 + ar) * K + ac;
    gA1 = gA0 + 64 * K;
  }
  const u16* gB0 = BT + (long)(n0 + ar) * K + ac;
  const u16* gB1 = gB0 + 64 * K;
  // trunk-1 fused inputs (MODE 1 only)
  float n0x = 0, n0y = 0, n0z = 0, n1x = 0, n1y = 0, n1z = 0;
  if constexpr (MODE == 1) {
    const float* nr0 = nodes3 + (m0 + ar) * 3;
    const float* nr1 = nodes3 + (m0 + ar + 64) * 3;
    n0x = nr0[0]; n0y = nr0[1]; n0z = nr0[2];
    n1x = nr1[0]; n1y = nr1[1]; n1z = nr1[2];
  }

  auto STAGE = [&](int kt, int b) {
    if constexpr (MODE == 1) {
      // A-tile computed: relu(nodes @ wt1[:, kt+ac .. +8] + bt1), written at the
      // linear slot (same position gl2lds would fill) -> layout matches reads.
      float w0[8], w1[8], w2[8], bb[8];
      const float* wp = wt1 + kt + ac;
      *(float4*)&w0[0] = *(const float4*)(wp);
      *(float4*)&w0[4] = *(const float4*)(wp + 4);
      *(float4*)&w1[0] = *(const float4*)(wp + 512);
      *(float4*)&w1[4] = *(const float4*)(wp + 516);
      *(float4*)&w2[0] = *(const float4*)(wp + 1024);
      *(float4*)&w2[4] = *(const float4*)(wp + 1028);
      *(float4*)&bb[0] = *(const float4*)(bt1 + kt + ac);
      *(float4*)&bb[4] = *(const float4*)(bt1 + kt + ac + 4);
      u16x8 o0, o1;
#pragma unroll
      for (int j = 0; j < 8; j++) {
        float v0 = fmaf(n0x, w0[j], fmaf(n0y, w1[j], fmaf(n0z, w2[j], bb[j])));
        float v1 = fmaf(n1x, w0[j], fmaf(n1y, w1[j], fmaf(n1z, w2[j], bb[j])));
        o0[j] = f2bf(fmaxf(v0, 0.0f));
        o1[j] = f2bf(fmaxf(v1, 0.0f));
      }
      *(u16x8*)&As[b][t * 8] = o0;
      *(u16x8*)&As[b][2048 + t * 8] = o1;
    } else {
      gl2lds16(gA0 + kt, &As[b][t * 8]);
      gl2lds16(gA1 + kt, &As[b][2048 + t * 8]);
    }
    gl2lds16(gB0 + kt, &Bs[b][t * 8]);
    gl2lds16(gB1 + kt, &Bs[b][2048 + t * 8]);
  };

  STAGE(0, 0);
  STAGE(32, 1);
  if constexpr (MODE == 1) asm volatile("s_waitcnt vmcnt(2) lgkmcnt(0)" ::: "memory");
  else                     asm volatile("s_waitcnt vmcnt(4) lgkmcnt(0)" ::: "memory");
  __builtin_amdgcn_s_barrier();

#pragma unroll
  for (int tt = 0; tt < NT; ++tt) {
    const int b = tt % 3;
    if (tt + 2 < NT) STAGE((tt + 2) * 32, (tt + 2) % 3);
    bf16x8 af[4], bfv[4];
#pragma unroll
    for (int i = 0; i < 4; i++) {
      af[i]  = *(const bf16x8*)&As[b][(wr * 64 + i * 16 + lr) * 32 + (kg ^ kx) * 8];
      bfv[i] = *(const bf16x8*)&Bs[b][(wc * 64 + i * 16 + lr) * 32 + (kg ^ kx) * 8];
    }
#pragma unroll
    for (int mi = 0; mi < 4; mi++)
#pragma unroll
      for (int ni = 0; ni < 4; ni++)
        acc[mi][ni] = __builtin_amdgcn_mfma_f32_16x16x32_bf16(af[mi], bfv[ni], acc[mi][ni], 0, 0, 0);
    if (tt + 1 < NT) {
      if (tt + 2 < NT) {
        if constexpr (MODE == 1) asm volatile("s_waitcnt vmcnt(2) lgkmcnt(0)" ::: "memory");
        else                     asm volatile("s_waitcnt vmcnt(4) lgkmcnt(0)" ::: "memory");
      } else {
        asm volatile("s_waitcnt vmcnt(0) lgkmcnt(0)" ::: "memory");
      }
      __builtin_amdgcn_s_barrier();
    }
  }

  if (MODE == 2) {
    // z2 = relu(acc + bo1); partial = z2 @ wo2 over this wave's 64 cols
    float po[4][4][3];
#pragma unroll
    for (int mi = 0; mi < 4; mi++)
#pragma unroll
      for (int r2 = 0; r2 < 4; r2++)
#pragma unroll
        for (int o = 0; o < 3; o++) po[mi][r2][o] = 0.0f;
#pragma unroll
    for (int ni = 0; ni < 4; ni++) {
      int col = n0 + wc * 64 + ni * 16 + lr;
      float bb = bias[col];
      float wa = wo2[col * 3 + 0], wb = wo2[col * 3 + 1], wcv = wo2[col * 3 + 2];
#pragma unroll
      for (int mi = 0; mi < 4; mi++)
#pragma unroll
        for (int r2 = 0; r2 < 4; r2++) {
          float v = fmaxf(acc[mi][ni][r2] + bb, 0.0f);
          po[mi][r2][0] = fmaf(v, wa, po[mi][r2][0]);
          po[mi][r2][1] = fmaf(v, wb, po[mi][r2][1]);
          po[mi][r2][2] = fmaf(v, wcv, po[mi][r2][2]);
        }
    }
#pragma unroll
    for (int s = 1; s < 16; s <<= 1)
#pragma unroll
      for (int mi = 0; mi < 4; mi++)
#pragma unroll
        for (int r2 = 0; r2 < 4; r2++)
#pragma unroll
          for (int o = 0; o < 3; o++) po[mi][r2][o] += __shfl_xor(po[mi][r2][o], s, 64);
    if (lr == 0) {
      const int slice = blockIdx.x * 2 + wc;
#pragma unroll
      for (int mi = 0; mi < 4; mi++)
#pragma unroll
        for (int r2 = 0; r2 < 4; r2++) {
          long grow = rowoff + m0 + wr * 64 + mi * 16 + kg * 4 + r2;
          float* p = outp + ((size_t)slice * NQVAL + grow) * 3;
          p[0] = po[mi][r2][0];
          p[1] = po[mi][r2][1];
          p[2] = po[mi][r2][2];
        }
    }
  } else {
    const int gq = (int)(m0 >> 13);  // 8192 query rows per graph
#pragma unroll
    for (int mi = 0; mi < 4; mi++)
#pragma unroll
      for (int ni = 0; ni < 4; ni++) {
        int col = n0 + wc * 64 + ni * 16 + lr;
        float bb = bias[col];
        float fm = (MODE == 1) ? field[gq * 512 + col] : 0.0f;
#pragma unroll
        for (int r2 = 0; r2 < 4; r2++) {
          long row = m0 + wr * 64 + mi * 16 + kg * 4 + r2;
          float v = acc[mi][ni][r2] + bb;
          v = (MODE == 1) ? v * fm : fmaxf(v, 0.0f);
          C[row * 512 + col] = f2bf(v);
        }
      }
  }
}

extern "C" void kernel_launch(void* const* d_in, const int* in_sizes, int n_in,
                              void* d_out, int out_size, void* d_ws, size_t ws_size,
                              hipStream_t stream) {
  const float* known = (const float*)d_in[0];
  const float* nodes = (const float*)d_in[1];
  const int* esrc = (const int*)d_in[2];
  const int* edst = (const int*)d_in[3];
  const float* gc_w0 = (const float*)d_in[6];
  const float* gc_b0 = (const float*)d_in[7];
  const float* gc_w1 = (const float*)d_in[8];
  const float* gc_b1 = (const float*)d_in[9];
  const float* gc_w2 = (const float*)d_in[10];
  const float* gc_b2 = (const float*)d_in[11];
  const float* gc_wr = (const float*)d_in[12];
  const float* gc_br = (const float*)d_in[13];
  const float* wt1 = (const float*)d_in[14];
  const float* bt1 = (const float*)d_in[15];
  const float* wt2 = (const float*)d_in[16];
  const float* bt2 = (const float*)d_in[17];
  const float* wo1 = (const float*)d_in[18];
  const float* bo1 = (const float*)d_in[19];
  const float* wo2 = (const float*)d_in[20];
  const float* bo2 = (const float*)d_in[21];
  float* out = (float*)d_out;
  (void)in_sizes; (void)n_in; (void)out_size;

  char* ws = (char*)d_ws;
  size_t off_b = 0;
  auto alloc = [&](size_t n) -> void* {
    void* p = ws + off_b;
    off_b += (n + 255) & ~(size_t)255;
    return p;
  };
  u16* w1T  = (u16*)alloc(512 * 512 * 2);
  u16* w2T  = (u16*)alloc(512 * 512 * 2);
  u16* wt2T = (u16*)alloc(512 * 512 * 2);
  u16* wo1T = (u16*)alloc(512 * 512 * 2);
  int* cnt   = (int*)alloc(NKVAL * 4);
  int* off   = (int*)alloc((NKVAL + 1) * 4);
  int* cur   = (int*)alloc(NKVAL * 4);
  int* srcs  = (int*)alloc((size_t)EVAL * 4);
  float* m0     = (float*)alloc(NKVAL * 3 * 4);
  float* pooled = (float*)alloc(32 * 512 * 4);
  float* field  = (float*)alloc(32 * 512 * 4);
  u16* bufA = (u16*)alloc((size_t)NKVAL * 512 * 2);  // aliased as outpart in query phase
  u16* bufB = (u16*)alloc((size_t)NKVAL * 512 * 2);
  u16* bufC = (u16*)alloc((size_t)NKVAL * 512 * 2);
  float* outpart = (float*)bufA;  // 8 slices x NQ x 3 f32 = 25.2MB <= 32MB

  // adaptive chunking for the query path (zc: chunk_rows KB)
  size_t rem = (ws_size > off_b) ? ws_size - off_b : 0;
  int chunk_rows = 32768;
  if ((size_t)262144 * 1024 <= rem) chunk_rows = 262144;
  else if ((size_t)131072 * 1024 <= rem) chunk_rows = 131072;
  else if ((size_t)65536 * 1024 <= rem) chunk_rows = 65536;
  u16* zc = (u16*)alloc((size_t)chunk_rows * 512 * 2);
  const int nch = NQVAL / chunk_rows;

  hipMemsetAsync(cnt, 0, NKVAL * 4, stream);
  hipMemsetAsync(cur, 0, NKVAL * 4, stream);
  hipMemsetAsync(pooled, 0, 32 * 512 * 4, stream);

  wcast_t<<<dim3(8, 8), 256, 0, stream>>>(gc_w1, w1T);
  wcast_t<<<dim3(8, 8), 256, 0, stream>>>(gc_w2, w2T);
  wcast_t<<<dim3(8, 8), 256, 0, stream>>>(wt2, wt2T);
  wcast_t<<<dim3(8, 8), 256, 0, stream>>>(wo1, wo1T);

  degcnt_k<<<EVAL / 256, 256, 0, stream>>>(edst, cnt);
  scan_k<<<1, 1024, 0, stream>>>(cnt, off);
  scatter_k<<<EVAL / 256, 256, 0, stream>>>(esrc, edst, off, cur, srcs);
  agg0_csr<<<NKVAL / 256, 256, 0, stream>>>(off, srcs, known, m0);

  // h0 = relu((m0/deg) @ gc_w0 + b0)
  k3_dense<<<NKVAL * 64 / 256, 256, 0, stream>>>(m0, cnt, gc_w0, gc_b0, bufA, NKVAL);
  // m1 = segsum(h0[src])/deg  (CSR gather, XCD-local)
  agg_csr<<<NKVAL / 4, 256, 0, stream>>>(bufA, off, srcs, bufB);
  // h1 = relu(m1 @ W1 + b1)
  gemm_bt<0><<<dim3(4, NKVAL / 128), 256, 0, stream>>>(bufB, w1T, gc_b1, nullptr, nullptr, bufC, nullptr, 0,
                                                       nullptr, nullptr, nullptr);
  // m2
  agg_csr<<<NKVAL / 4, 256, 0, stream>>>(bufC, off, srcs, bufA);
  // h2
  gemm_bt<0><<<dim3(4, NKVAL / 128), 256, 0, stream>>>(bufA, w2T, gc_b2, nullptr, nullptr, bufB, nullptr, 0,
                                                       nullptr, nullptr, nullptr);
  pool_k<<<dim3(8, 32), 256, 0, stream>>>(bufB, pooled);
  field_k<<<64, 256, 0, stream>>>(pooled, gc_wr, gc_br, field);

  for (int ch = 0; ch < nch; ch++) {
    long rowoff = (long)ch * chunk_rows;
    // z = (relu(nodes@wt1+bt1) @ wt2 + bt2) * field[seg]   (trunk-1 fused into staging)
    gemm_bt<1><<<dim3(4, chunk_rows / 128), 256, 0, stream>>>(nullptr, wt2T, bt2,
                                                              field + (rowoff >> 13) * 512, nullptr, zc, nullptr, 0,
                                                              nodes + rowoff * 3, wt1, bt1);
    // partial[slice] = relu(z @ wo1 + bo1) @ wo2   (per n-block/wave-col slice, no atomics)
    gemm_bt<2><<<dim3(4, chunk_rows / 128), 256, 0, stream>>>(zc, wo1T, bo1, nullptr, wo2, nullptr,
                                                              outpart, rowoff, nullptr, nullptr, nullptr);
  }
  // out = sum of 8 slices + bo2
  out_reduce<<<NQVAL * 3 / 256, 256, 0, stream>>>(outpart, bo2, out);
}